// Round 3
// baseline (354.910 us; speedup 1.0000x reference)
//
#include <hip/hip_runtime.h>
#include <cmath>

#define SSZ    128
#define SS     (SSZ*SSZ)
#define NB     8
#define NNODES (NB*SS)   /* 131072 */
#define DD     64
#define MM     16384
#define HH     100
#define BINCAP 64        /* max nodes per cluster bin; Binomial(131072,1/16384) max ~25 */

// ---------------------------------------------------------------------------
// K2: bin nodes by cluster. 131k scalar atomics on 16k counters — cheap.
// ---------------------------------------------------------------------------
__global__ void k_scatter(const int* __restrict__ cluster,
                          int* __restrict__ binCnt, int* __restrict__ nodeList) {
    int n = blockIdx.x * 256 + threadIdx.x;
    if (n >= NNODES) return;
    int c = cluster[n];
    int pos = atomicAdd(&binCnt[c], 1);
    if (pos < BINCAP) nodeList[c * BINCAP + pos] = n;
}

// ---------------------------------------------------------------------------
// K3: per-cluster segment mean. ONE BLOCK (8 waves) per cluster; waves split
// the member list for latency hiding, LDS tree-combine, plain stores.
// ---------------------------------------------------------------------------
__global__ __launch_bounds__(512) void k_reduce(
    const float* __restrict__ x, const float* __restrict__ coords,
    const int* __restrict__ binCnt, const int* __restrict__ nodeList,
    float* __restrict__ inAll, float* __restrict__ jsf) {
    __shared__ float px[8][64];
    __shared__ float pc[8][2];
    __shared__ float pm[8][2];
    const int wv = threadIdx.x >> 6, d = threadIdx.x & 63;
    const int c = blockIdx.x;
    int cnt = binCnt[c];
    if (cnt > BINCAP) cnt = BINCAP;
    float sx = 0.0f, sc = 0.0f, sm = 0.0f;
    for (int i = wv; i < cnt; i += 8) {
        int n = nodeList[c * BINCAP + i];
        sx += x[n * 64 + d];
        if (d < 2) { float cv = coords[n * 2 + d]; sc += cv; sm += cv * cv; }
    }
    px[wv][d] = sx;
    if (d < 2) { pc[wv][d] = sc; pm[wv][d] = sm; }
    __syncthreads();
    if (threadIdx.x < 64) {
        int t = threadIdx.x;
        float s = 0.0f;
        #pragma unroll
        for (int w = 0; w < 8; w++) s += px[w][t];
        float fcnt = fmaxf((float)cnt, 1.0f);
        inAll[c * 68 + t] = s / fcnt;
        if (t < 2) {
            float scs = 0.0f, sms = 0.0f;
            #pragma unroll
            for (int w = 0; w < 8; w++) { scs += pc[w][t]; sms += pm[w][t]; }
            float cent = scs / fcnt;
            inAll[c * 68 + 64 + t] = 10.0f * cent;
            inAll[c * 68 + 66 + t] = 10.0f * sms / fcnt;
            jsf[c * 20 + 18 + t] = cent;
        }
    }
}

// ---------------------------------------------------------------------------
// K4: per-cluster MLP1 (68->100->100->64) fused with h@Wn and h@Wr+bg.
// 8 clusters per block of 128 threads; thread j owns output unit j.
// ---------------------------------------------------------------------------
__global__ __launch_bounds__(128) void k_mlp1(
    const float* __restrict__ inAll,
    const float* __restrict__ W1, const float* __restrict__ b1,
    const float* __restrict__ W2, const float* __restrict__ b2,
    const float* __restrict__ W3, const float* __restrict__ b3,
    const float* __restrict__ Wn, const float* __restrict__ Wr,
    const float* __restrict__ bg,
    float* __restrict__ hWnOut, float* __restrict__ featP) {
    __shared__ float inL[8][68];
    __shared__ float h1[8][HH];
    __shared__ float h2[8][HH];
    __shared__ float hL[8][DD];
    const int c0 = blockIdx.x * 8;
    const int t  = threadIdx.x;

    for (int idx = t; idx < 8 * 68; idx += 128) {
        int ci = idx / 68, k = idx - ci * 68;
        inL[ci][k] = inAll[(c0 + ci) * 68 + k];
    }
    __syncthreads();

    if (t < HH) {                            // stage 1: 68 -> 100, relu
        float acc[8];
        float bb = b1[t];
        #pragma unroll
        for (int ci = 0; ci < 8; ci++) acc[ci] = bb;
        for (int k = 0; k < 68; k++) {
            float w = W1[k * HH + t];
            #pragma unroll
            for (int ci = 0; ci < 8; ci++) acc[ci] += inL[ci][k] * w;
        }
        #pragma unroll
        for (int ci = 0; ci < 8; ci++) h1[ci][t] = fmaxf(acc[ci], 0.0f);
    }
    __syncthreads();

    if (t < HH) {                            // stage 2: 100 -> 100, relu
        float acc[8];
        float bb = b2[t];
        #pragma unroll
        for (int ci = 0; ci < 8; ci++) acc[ci] = bb;
        for (int k = 0; k < HH; k++) {
            float w = W2[k * HH + t];
            #pragma unroll
            for (int ci = 0; ci < 8; ci++) acc[ci] += h1[ci][k] * w;
        }
        #pragma unroll
        for (int ci = 0; ci < 8; ci++) h2[ci][t] = fmaxf(acc[ci], 0.0f);
    }
    __syncthreads();

    if (t < DD) {                            // stage 3: 100 -> 64 (no relu)
        float acc[8];
        float bb = b3[t];
        #pragma unroll
        for (int ci = 0; ci < 8; ci++) acc[ci] = bb;
        for (int k = 0; k < HH; k++) {
            float w = W3[k * DD + t];
            #pragma unroll
            for (int ci = 0; ci < 8; ci++) acc[ci] += h2[ci][k] * w;
        }
        #pragma unroll
        for (int ci = 0; ci < 8; ci++) hL[ci][t] = acc[ci];
    }
    __syncthreads();

    if (t < DD) {                            // stage 4: h@Wn and h@Wr + bg
        float an[8], ar[8];
        float bgv = bg[t];
        #pragma unroll
        for (int ci = 0; ci < 8; ci++) { an[ci] = 0.0f; ar[ci] = bgv; }
        for (int k = 0; k < DD; k++) {
            float wn = Wn[k * DD + t];
            float wr = Wr[k * DD + t];
            #pragma unroll
            for (int ci = 0; ci < 8; ci++) {
                float hv = hL[ci][k];
                an[ci] += hv * wn;
                ar[ci] += hv * wr;
            }
        }
        #pragma unroll
        for (int ci = 0; ci < 8; ci++) {
            hWnOut[(c0 + ci) * DD + t] = an[ci];
            featP [(c0 + ci) * DD + t] = ar[ci];
        }
    }
}

// ---------------------------------------------------------------------------
// K5: edge segment-max, no atomics. ONE BLOCK (8 waves) per destination
// cluster; waves split the member list (each member contributes its L=1 3x3
// stencil == the edge list), LDS max-combine, one plain store per dim.
// ---------------------------------------------------------------------------
__global__ __launch_bounds__(512) void k_edgemax(
    const int* __restrict__ cluster,
    const int* __restrict__ binCnt, const int* __restrict__ nodeList,
    const float* __restrict__ hWn,
    float* __restrict__ aggF) {
    __shared__ float pmx[8][64];
    const int wv = threadIdx.x >> 6, d = threadIdx.x & 63;
    const int c = blockIdx.x;
    int cnt = binCnt[c];
    if (cnt > BINCAP) cnt = BINCAP;
    float m = -__builtin_inff();
    for (int i = wv; i < cnt; i += 8) {
        int n = nodeList[c * BINCAP + i];    // wave-uniform
        int b = n >> 14;                     // n / SS
        int p = n & (SS - 1);
        int ii = p >> 7, jj = p & 127;
        #pragma unroll
        for (int di = -1; di <= 1; di++) {
            int i2 = ii + di;
            if (i2 < 0 || i2 >= SSZ) continue;   // wave-uniform branch
            #pragma unroll
            for (int dj = -1; dj <= 1; dj++) {
                int j2 = jj + dj;
                if (j2 < 0 || j2 >= SSZ) continue;
                int s  = b * SS + i2 * SSZ + j2;
                int cs = cluster[s];             // wave-uniform -> broadcast
                m = fmaxf(m, hWn[cs * 64 + d]);
            }
        }
    }
    pmx[wv][d] = m;
    __syncthreads();
    if (threadIdx.x < 64) {
        int t = threadIdx.x;
        float mm = pmx[0][t];
        #pragma unroll
        for (int w = 1; w < 8; w++) mm = fmaxf(mm, pmx[w][t]);
        aggF[c * 64 + t] = (cnt == 0) ? 0.0f : mm;   // empty segment -> 0
    }
}

// ---------------------------------------------------------------------------
// K6: per-cluster Q-MLP (64->100->100->100->18) -> jsf cols 0..17
// ---------------------------------------------------------------------------
__global__ __launch_bounds__(128) void k_qmlp(
    const float* __restrict__ featP, const float* __restrict__ aggF,
    const float* __restrict__ Q1w, const float* __restrict__ Q1b,
    const float* __restrict__ Q2w, const float* __restrict__ Q2b,
    const float* __restrict__ Q3w, const float* __restrict__ Q3b,
    const float* __restrict__ Q4w, const float* __restrict__ Q4b,
    float* __restrict__ jsf) {
    __shared__ float fL[8][DD];
    __shared__ float h1[8][HH];
    __shared__ float h2[8][HH];
    const int c0 = blockIdx.x * 8;
    const int t  = threadIdx.x;

    for (int idx = t; idx < 8 * DD; idx += 128) {
        int ci = idx >> 6, k = idx & 63;
        int c = c0 + ci;
        fL[ci][k] = featP[c * 64 + k] + aggF[c * 64 + k];
    }
    __syncthreads();

    if (t < HH) {                            // Q1: 64 -> 100, relu
        float acc[8];
        float bb = Q1b[t];
        #pragma unroll
        for (int ci = 0; ci < 8; ci++) acc[ci] = bb;
        for (int k = 0; k < DD; k++) {
            float w = Q1w[k * HH + t];
            #pragma unroll
            for (int ci = 0; ci < 8; ci++) acc[ci] += fL[ci][k] * w;
        }
        #pragma unroll
        for (int ci = 0; ci < 8; ci++) h1[ci][t] = fmaxf(acc[ci], 0.0f);
    }
    __syncthreads();

    if (t < HH) {                            // Q2: 100 -> 100, relu
        float acc[8];
        float bb = Q2b[t];
        #pragma unroll
        for (int ci = 0; ci < 8; ci++) acc[ci] = bb;
        for (int k = 0; k < HH; k++) {
            float w = Q2w[k * HH + t];
            #pragma unroll
            for (int ci = 0; ci < 8; ci++) acc[ci] += h1[ci][k] * w;
        }
        #pragma unroll
        for (int ci = 0; ci < 8; ci++) h2[ci][t] = fmaxf(acc[ci], 0.0f);
    }
    __syncthreads();

    if (t < HH) {                            // Q3: 100 -> 100, relu (into h1)
        float acc[8];
        float bb = Q3b[t];
        #pragma unroll
        for (int ci = 0; ci < 8; ci++) acc[ci] = bb;
        for (int k = 0; k < HH; k++) {
            float w = Q3w[k * HH + t];
            #pragma unroll
            for (int ci = 0; ci < 8; ci++) acc[ci] += h2[ci][k] * w;
        }
        #pragma unroll
        for (int ci = 0; ci < 8; ci++) h1[ci][t] = fmaxf(acc[ci], 0.0f);
    }
    __syncthreads();

    if (t < 18) {                            // Q4: 100 -> 18
        float acc[8];
        float bb = Q4b[t];
        #pragma unroll
        for (int ci = 0; ci < 8; ci++) acc[ci] = bb;
        for (int k = 0; k < HH; k++) {
            float w = Q4w[k * 18 + t];
            #pragma unroll
            for (int ci = 0; ci < 8; ci++) acc[ci] += h1[ci][k] * w;
        }
        #pragma unroll
        for (int ci = 0; ci < 8; ci++) jsf[(c0 + ci) * 20 + t] = acc[ci];
    }
}

// ---------------------------------------------------------------------------
// K7: per-node quadratic render
// ---------------------------------------------------------------------------
__global__ void k_render(const float* __restrict__ jsf, const int* __restrict__ cluster,
                         const float* __restrict__ coords, float* __restrict__ out) {
    int n = blockIdx.x * 256 + threadIdx.x;
    if (n >= NNODES) return;
    int c = cluster[n];
    const float* f = &jsf[c * 20];
    float gx = coords[n * 2 + 0], gy = coords[n * 2 + 1];
    float dx = gx - f[0];
    float dy = gy - f[1];
    #pragma unroll
    for (int r = 0; r < 3; r++) {
        float a   = f[2 + r * 6 + 0];
        float ah  = f[2 + r * 6 + 1];
        float aw  = f[2 + r * 6 + 2];
        float ahh = f[2 + r * 6 + 3];
        float aww = f[2 + r * 6 + 4];
        float ahw = f[2 + r * 6 + 5];
        out[n * 3 + r] = a + ah * dx + aw * dy + ahh * dx * dx + aww * dy * dy + ahw * dx * dy;
    }
}

// ---------------------------------------------------------------------------
extern "C" void kernel_launch(void* const* d_in, const int* in_sizes, int n_in,
                              void* d_out, int out_size, void* d_ws, size_t ws_size,
                              hipStream_t stream) {
    const float* x       = (const float*)d_in[0];
    const float* coords  = (const float*)d_in[1];
    const int*   cluster = (const int*)  d_in[2];
    // d_in[3], d_in[4]: edge_src/edge_dst — reconstructed analytically (L=1 stencil)
    const float* W1  = (const float*)d_in[5];
    const float* b1  = (const float*)d_in[6];
    const float* W2  = (const float*)d_in[7];
    const float* b2  = (const float*)d_in[8];
    const float* W3  = (const float*)d_in[9];
    const float* b3  = (const float*)d_in[10];
    const float* Wr  = (const float*)d_in[11];
    const float* Wn  = (const float*)d_in[12];
    const float* bg  = (const float*)d_in[13];
    const float* Q1w = (const float*)d_in[14];
    const float* Q1b = (const float*)d_in[15];
    const float* Q2w = (const float*)d_in[16];
    const float* Q2b = (const float*)d_in[17];
    const float* Q3w = (const float*)d_in[18];
    const float* Q3b = (const float*)d_in[19];
    const float* Q4w = (const float*)d_in[20];
    const float* Q4b = (const float*)d_in[21];
    float* out = (float*)d_out;

    // workspace layout (4-byte units):
    // [binCnt M][nodeList M*BINCAP][inAll M*68][featP M*64][hWn M*64][aggF M*64][jsf M*20]
    int*   binCnt   = (int*)d_ws;
    int*   nodeList = binCnt + MM;
    float* inAll    = (float*)(nodeList + MM * BINCAP);
    float* featP    = inAll + MM * 68;
    float* hWn      = featP + MM * 64;
    float* aggF     = hWn   + MM * 64;
    float* jsf      = aggF  + MM * 64;

    hipMemsetAsync(binCnt, 0, MM * sizeof(int), stream);
    k_scatter<<<(NNODES + 255) / 256, 256, 0, stream>>>(cluster, binCnt, nodeList);
    k_reduce <<<MM, 512, 0, stream>>>(x, coords, binCnt, nodeList, inAll, jsf);
    k_mlp1   <<<MM / 8, 128, 0, stream>>>(inAll, W1, b1, W2, b2, W3, b3, Wn, Wr, bg, hWn, featP);
    k_edgemax<<<MM, 512, 0, stream>>>(cluster, binCnt, nodeList, hWn, aggF);
    k_qmlp   <<<MM / 8, 128, 0, stream>>>(featP, aggF, Q1w, Q1b, Q2w, Q2b, Q3w, Q3b, Q4w, Q4b, jsf);
    k_render <<<(NNODES + 255) / 256, 256, 0, stream>>>(jsf, cluster, coords, out);
}

// Round 4
// 285.618 us; speedup vs baseline: 1.2426x; 1.2426x over previous
//
#include <hip/hip_runtime.h>
#include <hip/hip_fp16.h>
#include <cmath>

#define SSZ    128
#define SS     (SSZ*SSZ)
#define NB     8
#define NNODES (NB*SS)   /* 131072 */
#define DD     64
#define MM     16384
#define HH     100
#define BINCAP 64        /* max nodes per cluster bin; Binomial(131072,1/16384) max ~25 */

// ---------------------------------------------------------------------------
// K2: bin nodes by cluster. 131k scalar atomics on 16k counters — cheap.
// ---------------------------------------------------------------------------
__global__ void k_scatter(const int* __restrict__ cluster,
                          int* __restrict__ binCnt, int* __restrict__ nodeList) {
    int n = blockIdx.x * 256 + threadIdx.x;
    if (n >= NNODES) return;
    int c = cluster[n];
    int pos = atomicAdd(&binCnt[c], 1);
    if (pos < BINCAP) nodeList[c * BINCAP + pos] = n;
}

// ---------------------------------------------------------------------------
// K3: per-cluster segment mean. One block (8 waves) per cluster; waves split
// the member list, LDS tree-combine, plain stores.
// ---------------------------------------------------------------------------
__global__ __launch_bounds__(512) void k_reduce(
    const float* __restrict__ x, const float* __restrict__ coords,
    const int* __restrict__ binCnt, const int* __restrict__ nodeList,
    float* __restrict__ inAll, float* __restrict__ jsf) {
    __shared__ float px[8][64];
    __shared__ float pc[8][2];
    __shared__ float pm[8][2];
    const int wv = threadIdx.x >> 6, d = threadIdx.x & 63;
    const int c = blockIdx.x;
    int cnt = binCnt[c];
    if (cnt > BINCAP) cnt = BINCAP;
    float sx = 0.0f, sc = 0.0f, sm = 0.0f;
    for (int i = wv; i < cnt; i += 8) {
        int n = nodeList[c * BINCAP + i];
        sx += x[n * 64 + d];
        if (d < 2) { float cv = coords[n * 2 + d]; sc += cv; sm += cv * cv; }
    }
    px[wv][d] = sx;
    if (d < 2) { pc[wv][d] = sc; pm[wv][d] = sm; }
    __syncthreads();
    if (threadIdx.x < 64) {
        int t = threadIdx.x;
        float s = 0.0f;
        #pragma unroll
        for (int w = 0; w < 8; w++) s += px[w][t];
        float fcnt = fmaxf((float)cnt, 1.0f);
        inAll[c * 68 + t] = s / fcnt;
        if (t < 2) {
            float scs = 0.0f, sms = 0.0f;
            #pragma unroll
            for (int w = 0; w < 8; w++) { scs += pc[w][t]; sms += pm[w][t]; }
            float cent = scs / fcnt;
            inAll[c * 68 + 64 + t] = 10.0f * cent;
            inAll[c * 68 + 66 + t] = 10.0f * sms / fcnt;
            jsf[c * 20 + 18 + t] = cent;
        }
    }
}

// ---------------------------------------------------------------------------
// K4: per-cluster MLP1 (68->100->100->64) fused with h@Wn (fp16 out) and
// h@Wr+bg. 8 clusters per block of 128 threads; thread j owns output unit j.
// ---------------------------------------------------------------------------
__global__ __launch_bounds__(128) void k_mlp1(
    const float* __restrict__ inAll,
    const float* __restrict__ W1, const float* __restrict__ b1,
    const float* __restrict__ W2, const float* __restrict__ b2,
    const float* __restrict__ W3, const float* __restrict__ b3,
    const float* __restrict__ Wn, const float* __restrict__ Wr,
    const float* __restrict__ bg,
    __half* __restrict__ hWnOut, float* __restrict__ featP) {
    __shared__ float inL[8][68];
    __shared__ float h1[8][HH];
    __shared__ float h2[8][HH];
    __shared__ float hL[8][DD];
    const int c0 = blockIdx.x * 8;
    const int t  = threadIdx.x;

    for (int idx = t; idx < 8 * 68; idx += 128) {
        int ci = idx / 68, k = idx - ci * 68;
        inL[ci][k] = inAll[(c0 + ci) * 68 + k];
    }
    __syncthreads();

    if (t < HH) {                            // stage 1: 68 -> 100, relu
        float acc[8];
        float bb = b1[t];
        #pragma unroll
        for (int ci = 0; ci < 8; ci++) acc[ci] = bb;
        for (int k = 0; k < 68; k++) {
            float w = W1[k * HH + t];
            #pragma unroll
            for (int ci = 0; ci < 8; ci++) acc[ci] += inL[ci][k] * w;
        }
        #pragma unroll
        for (int ci = 0; ci < 8; ci++) h1[ci][t] = fmaxf(acc[ci], 0.0f);
    }
    __syncthreads();

    if (t < HH) {                            // stage 2: 100 -> 100, relu
        float acc[8];
        float bb = b2[t];
        #pragma unroll
        for (int ci = 0; ci < 8; ci++) acc[ci] = bb;
        for (int k = 0; k < HH; k++) {
            float w = W2[k * HH + t];
            #pragma unroll
            for (int ci = 0; ci < 8; ci++) acc[ci] += h1[ci][k] * w;
        }
        #pragma unroll
        for (int ci = 0; ci < 8; ci++) h2[ci][t] = fmaxf(acc[ci], 0.0f);
    }
    __syncthreads();

    if (t < DD) {                            // stage 3: 100 -> 64 (no relu)
        float acc[8];
        float bb = b3[t];
        #pragma unroll
        for (int ci = 0; ci < 8; ci++) acc[ci] = bb;
        for (int k = 0; k < HH; k++) {
            float w = W3[k * DD + t];
            #pragma unroll
            for (int ci = 0; ci < 8; ci++) acc[ci] += h2[ci][k] * w;
        }
        #pragma unroll
        for (int ci = 0; ci < 8; ci++) hL[ci][t] = acc[ci];
    }
    __syncthreads();

    if (t < DD) {                            // stage 4: h@Wn (fp16) and h@Wr+bg
        float an[8], ar[8];
        float bgv = bg[t];
        #pragma unroll
        for (int ci = 0; ci < 8; ci++) { an[ci] = 0.0f; ar[ci] = bgv; }
        for (int k = 0; k < DD; k++) {
            float wn = Wn[k * DD + t];
            float wr = Wr[k * DD + t];
            #pragma unroll
            for (int ci = 0; ci < 8; ci++) {
                float hv = hL[ci][k];
                an[ci] += hv * wn;
                ar[ci] += hv * wr;
            }
        }
        #pragma unroll
        for (int ci = 0; ci < 8; ci++) {
            hWnOut[(c0 + ci) * DD + t] = __float2half(an[ci]);
            featP [(c0 + ci) * DD + t] = ar[ci];
        }
    }
}

// ---------------------------------------------------------------------------
// K5a: horizontal 3-max of g[n] = hWn[cluster[n]] along image rows.
// One wave per 16-column chunk: ONE vector load of the 18 cluster ids
// (lanes 0..17), shfl-broadcast, 18 INDEPENDENT hWn row gathers (no chain),
// 16 fp16 row stores. Shares each gather across 3 window positions.
// ---------------------------------------------------------------------------
__global__ __launch_bounds__(256) void k_hmax(
    const int* __restrict__ cluster, const __half* __restrict__ hWn,
    __half* __restrict__ hmax) {
    const int w    = blockIdx.x * 4 + (threadIdx.x >> 6);   // 8192 waves
    const int lane = threadIdx.x & 63;
    const int b    = w >> 10;            // 1024 waves per image (128 rows x 8)
    const int rem  = w & 1023;
    const int i    = rem >> 3;
    const int j0   = (rem & 7) << 4;
    const int base = b * SS + i * SSZ;

    int jl  = j0 - 1 + lane;
    int cid = 0;
    if (lane < 18 && jl >= 0 && jl < SSZ) cid = cluster[base + jl];

    float val[18];
    #pragma unroll
    for (int p = 0; p < 18; p++) {
        int jp = j0 - 1 + p;
        int cp = __shfl(cid, p);
        if (jp >= 0 && jp < SSZ)
            val[p] = __half2float(hWn[(cp << 6) + lane]);
        else
            val[p] = -__builtin_inff();
    }

    const int outbase = (base + j0) << 6;
    #pragma unroll
    for (int k = 0; k < 16; k++) {
        float m = fmaxf(fmaxf(val[k], val[k + 1]), val[k + 2]);
        hmax[outbase + (k << 6) + lane] = __float2half(m);
    }
}

// ---------------------------------------------------------------------------
// K5b: vertical 3-max + per-cluster segment max, fused. One block (8 waves)
// per destination cluster; each member contributes max over hmax rows
// i-1..i+1 (3 independent 128B gathers from the L3-resident fp16 buffer).
// ---------------------------------------------------------------------------
__global__ __launch_bounds__(512) void k_vcmax(
    const int* __restrict__ binCnt, const int* __restrict__ nodeList,
    const __half* __restrict__ hmax, float* __restrict__ aggF) {
    __shared__ float pmx[8][64];
    const int wv = threadIdx.x >> 6, d = threadIdx.x & 63;
    const int c = blockIdx.x;
    int cnt = binCnt[c];
    if (cnt > BINCAP) cnt = BINCAP;
    float m = -__builtin_inff();
    for (int i = wv; i < cnt; i += 8) {
        int n = nodeList[c * BINCAP + i];    // wave-uniform
        int b = n >> 14;
        int p = n & (SS - 1);
        int ii = p >> 7, jj = p & 127;
        #pragma unroll
        for (int di = -1; di <= 1; di++) {
            int i2 = ii + di;
            if (i2 < 0 || i2 >= SSZ) continue;   // wave-uniform
            m = fmaxf(m, __half2float(hmax[((b * SS + i2 * SSZ + jj) << 6) + d]));
        }
    }
    pmx[wv][d] = m;
    __syncthreads();
    if (threadIdx.x < 64) {
        int t = threadIdx.x;
        float mm = pmx[0][t];
        #pragma unroll
        for (int w = 1; w < 8; w++) mm = fmaxf(mm, pmx[w][t]);
        aggF[c * 64 + t] = (cnt == 0) ? 0.0f : mm;   // empty segment -> 0
    }
}

// ---------------------------------------------------------------------------
// K6: per-cluster Q-MLP (64->100->100->100->18) -> jsf cols 0..17
// ---------------------------------------------------------------------------
__global__ __launch_bounds__(128) void k_qmlp(
    const float* __restrict__ featP, const float* __restrict__ aggF,
    const float* __restrict__ Q1w, const float* __restrict__ Q1b,
    const float* __restrict__ Q2w, const float* __restrict__ Q2b,
    const float* __restrict__ Q3w, const float* __restrict__ Q3b,
    const float* __restrict__ Q4w, const float* __restrict__ Q4b,
    float* __restrict__ jsf) {
    __shared__ float fL[8][DD];
    __shared__ float h1[8][HH];
    __shared__ float h2[8][HH];
    const int c0 = blockIdx.x * 8;
    const int t  = threadIdx.x;

    for (int idx = t; idx < 8 * DD; idx += 128) {
        int ci = idx >> 6, k = idx & 63;
        int c = c0 + ci;
        fL[ci][k] = featP[c * 64 + k] + aggF[c * 64 + k];
    }
    __syncthreads();

    if (t < HH) {                            // Q1: 64 -> 100, relu
        float acc[8];
        float bb = Q1b[t];
        #pragma unroll
        for (int ci = 0; ci < 8; ci++) acc[ci] = bb;
        for (int k = 0; k < DD; k++) {
            float w = Q1w[k * HH + t];
            #pragma unroll
            for (int ci = 0; ci < 8; ci++) acc[ci] += fL[ci][k] * w;
        }
        #pragma unroll
        for (int ci = 0; ci < 8; ci++) h1[ci][t] = fmaxf(acc[ci], 0.0f);
    }
    __syncthreads();

    if (t < HH) {                            // Q2: 100 -> 100, relu
        float acc[8];
        float bb = Q2b[t];
        #pragma unroll
        for (int ci = 0; ci < 8; ci++) acc[ci] = bb;
        for (int k = 0; k < HH; k++) {
            float w = Q2w[k * HH + t];
            #pragma unroll
            for (int ci = 0; ci < 8; ci++) acc[ci] += h1[ci][k] * w;
        }
        #pragma unroll
        for (int ci = 0; ci < 8; ci++) h2[ci][t] = fmaxf(acc[ci], 0.0f);
    }
    __syncthreads();

    if (t < HH) {                            // Q3: 100 -> 100, relu (into h1)
        float acc[8];
        float bb = Q3b[t];
        #pragma unroll
        for (int ci = 0; ci < 8; ci++) acc[ci] = bb;
        for (int k = 0; k < HH; k++) {
            float w = Q3w[k * HH + t];
            #pragma unroll
            for (int ci = 0; ci < 8; ci++) acc[ci] += h2[ci][k] * w;
        }
        #pragma unroll
        for (int ci = 0; ci < 8; ci++) h1[ci][t] = fmaxf(acc[ci], 0.0f);
    }
    __syncthreads();

    if (t < 18) {                            // Q4: 100 -> 18
        float acc[8];
        float bb = Q4b[t];
        #pragma unroll
        for (int ci = 0; ci < 8; ci++) acc[ci] = bb;
        for (int k = 0; k < HH; k++) {
            float w = Q4w[k * 18 + t];
            #pragma unroll
            for (int ci = 0; ci < 8; ci++) acc[ci] += h1[ci][k] * w;
        }
        #pragma unroll
        for (int ci = 0; ci < 8; ci++) jsf[(c0 + ci) * 20 + t] = acc[ci];
    }
}

// ---------------------------------------------------------------------------
// K7: per-node quadratic render
// ---------------------------------------------------------------------------
__global__ void k_render(const float* __restrict__ jsf, const int* __restrict__ cluster,
                         const float* __restrict__ coords, float* __restrict__ out) {
    int n = blockIdx.x * 256 + threadIdx.x;
    if (n >= NNODES) return;
    int c = cluster[n];
    const float* f = &jsf[c * 20];
    float gx = coords[n * 2 + 0], gy = coords[n * 2 + 1];
    float dx = gx - f[0];
    float dy = gy - f[1];
    #pragma unroll
    for (int r = 0; r < 3; r++) {
        float a   = f[2 + r * 6 + 0];
        float ah  = f[2 + r * 6 + 1];
        float aw  = f[2 + r * 6 + 2];
        float ahh = f[2 + r * 6 + 3];
        float aww = f[2 + r * 6 + 4];
        float ahw = f[2 + r * 6 + 5];
        out[n * 3 + r] = a + ah * dx + aw * dy + ahh * dx * dx + aww * dy * dy + ahw * dx * dy;
    }
}

// ---------------------------------------------------------------------------
extern "C" void kernel_launch(void* const* d_in, const int* in_sizes, int n_in,
                              void* d_out, int out_size, void* d_ws, size_t ws_size,
                              hipStream_t stream) {
    const float* x       = (const float*)d_in[0];
    const float* coords  = (const float*)d_in[1];
    const int*   cluster = (const int*)  d_in[2];
    // d_in[3], d_in[4]: edge_src/edge_dst — reconstructed analytically (L=1 stencil)
    const float* W1  = (const float*)d_in[5];
    const float* b1  = (const float*)d_in[6];
    const float* W2  = (const float*)d_in[7];
    const float* b2  = (const float*)d_in[8];
    const float* W3  = (const float*)d_in[9];
    const float* b3  = (const float*)d_in[10];
    const float* Wr  = (const float*)d_in[11];
    const float* Wn  = (const float*)d_in[12];
    const float* bg  = (const float*)d_in[13];
    const float* Q1w = (const float*)d_in[14];
    const float* Q1b = (const float*)d_in[15];
    const float* Q2w = (const float*)d_in[16];
    const float* Q2b = (const float*)d_in[17];
    const float* Q3w = (const float*)d_in[18];
    const float* Q3b = (const float*)d_in[19];
    const float* Q4w = (const float*)d_in[20];
    const float* Q4b = (const float*)d_in[21];
    float* out = (float*)d_out;

    // workspace layout (4-byte units, fp16 tail):
    // [binCnt M][nodeList M*64][inAll M*68][featP M*64][aggF M*64][jsf M*20]
    // [hWnH M*64 half][hmaxH N*64 half]   (~37 MB total)
    int*    binCnt   = (int*)d_ws;
    int*    nodeList = binCnt + MM;
    float*  inAll    = (float*)(nodeList + MM * BINCAP);
    float*  featP    = inAll + MM * 68;
    float*  aggF     = featP + MM * 64;
    float*  jsf      = aggF  + MM * 64;
    __half* hWnH     = (__half*)(jsf + MM * 20);
    __half* hmaxH    = hWnH + MM * 64;

    hipMemsetAsync(binCnt, 0, MM * sizeof(int), stream);
    k_scatter<<<(NNODES + 255) / 256, 256, 0, stream>>>(cluster, binCnt, nodeList);
    k_reduce <<<MM, 512, 0, stream>>>(x, coords, binCnt, nodeList, inAll, jsf);
    k_mlp1   <<<MM / 8, 128, 0, stream>>>(inAll, W1, b1, W2, b2, W3, b3, Wn, Wr, bg, hWnH, featP);
    k_hmax   <<<2048, 256, 0, stream>>>(cluster, hWnH, hmaxH);
    k_vcmax  <<<MM, 512, 0, stream>>>(binCnt, nodeList, hmaxH, aggF);
    k_qmlp   <<<MM / 8, 128, 0, stream>>>(featP, aggF, Q1w, Q1b, Q2w, Q2b, Q3w, Q3b, Q4w, Q4b, jsf);
    k_render <<<(NNODES + 255) / 256, 256, 0, stream>>>(jsf, cluster, coords, out);
}

// Round 5
// 264.169 us; speedup vs baseline: 1.3435x; 1.0812x over previous
//
#include <hip/hip_runtime.h>
#include <hip/hip_fp16.h>
#include <cmath>

#define SSZ    128
#define SS     (SSZ*SSZ)
#define NB     8
#define NNODES (NB*SS)   /* 131072 */
#define DD     64
#define MM     16384
#define HH     100
#define BINCAP 64        /* max nodes per cluster bin; Binomial(131072,1/16384) max ~25 */

// ---------------------------------------------------------------------------
// K2: bin nodes by cluster. 131k scalar atomics on 16k counters — cheap.
// ---------------------------------------------------------------------------
__global__ void k_scatter(const int* __restrict__ cluster,
                          int* __restrict__ binCnt, int* __restrict__ nodeList) {
    int n = blockIdx.x * 256 + threadIdx.x;
    if (n >= NNODES) return;
    int c = cluster[n];
    int pos = atomicAdd(&binCnt[c], 1);
    if (pos < BINCAP) nodeList[c * BINCAP + pos] = n;
}

// ---------------------------------------------------------------------------
// K3: per-cluster segment mean. One block (8 waves) per cluster; waves split
// the member list, LDS tree-combine, plain stores.
// ---------------------------------------------------------------------------
__global__ __launch_bounds__(512) void k_reduce(
    const float* __restrict__ x, const float* __restrict__ coords,
    const int* __restrict__ binCnt, const int* __restrict__ nodeList,
    float* __restrict__ inAll, float* __restrict__ jsf) {
    __shared__ float px[8][64];
    __shared__ float pc[8][2];
    __shared__ float pm[8][2];
    const int wv = threadIdx.x >> 6, d = threadIdx.x & 63;
    const int c = blockIdx.x;
    int cnt = binCnt[c];
    if (cnt > BINCAP) cnt = BINCAP;
    float sx = 0.0f, sc = 0.0f, sm = 0.0f;
    for (int i = wv; i < cnt; i += 8) {
        int n = nodeList[c * BINCAP + i];
        sx += x[n * 64 + d];
        if (d < 2) { float cv = coords[n * 2 + d]; sc += cv; sm += cv * cv; }
    }
    px[wv][d] = sx;
    if (d < 2) { pc[wv][d] = sc; pm[wv][d] = sm; }
    __syncthreads();
    if (threadIdx.x < 64) {
        int t = threadIdx.x;
        float s = 0.0f;
        #pragma unroll
        for (int w = 0; w < 8; w++) s += px[w][t];
        float fcnt = fmaxf((float)cnt, 1.0f);
        inAll[c * 68 + t] = s / fcnt;
        if (t < 2) {
            float scs = 0.0f, sms = 0.0f;
            #pragma unroll
            for (int w = 0; w < 8; w++) { scs += pc[w][t]; sms += pm[w][t]; }
            float cent = scs / fcnt;
            inAll[c * 68 + 64 + t] = 10.0f * cent;
            inAll[c * 68 + 66 + t] = 10.0f * sms / fcnt;
            jsf[c * 20 + 18 + t] = cent;
        }
    }
}

// 8-wide FMA from two float4 LDS broadcasts (conflict-free: same addr all lanes)
#define FMA8(arr, k, w, acc)                                                   \
    {                                                                          \
        float4 _p = *(const float4*)&arr[k][0];                                \
        float4 _q = *(const float4*)&arr[k][4];                                \
        acc[0] += _p.x * w; acc[1] += _p.y * w;                                \
        acc[2] += _p.z * w; acc[3] += _p.w * w;                                \
        acc[4] += _q.x * w; acc[5] += _q.y * w;                                \
        acc[6] += _q.z * w; acc[7] += _q.w * w;                                \
    }

#define STORE8_RELU(arr, t, acc)                                               \
    {                                                                          \
        *(float4*)&arr[t][0] = make_float4(fmaxf(acc[0], 0.0f),                \
            fmaxf(acc[1], 0.0f), fmaxf(acc[2], 0.0f), fmaxf(acc[3], 0.0f));    \
        *(float4*)&arr[t][4] = make_float4(fmaxf(acc[4], 0.0f),                \
            fmaxf(acc[5], 0.0f), fmaxf(acc[6], 0.0f), fmaxf(acc[7], 0.0f));    \
    }

// ---------------------------------------------------------------------------
// K4: per-cluster MLP1 (68->100->100->64) fused with h@Wn (fp16 out) and
// h@Wr+bg. 8 clusters per block of 128 threads; thread j owns output unit j.
// LDS activations stored TRANSPOSED [k][cluster] so the 8 cluster values per
// k are one 32B broadcast (2x ds_read_b128) instead of 8x ds_read_b32.
// ---------------------------------------------------------------------------
__global__ __launch_bounds__(128) void k_mlp1(
    const float* __restrict__ inAll,
    const float* __restrict__ W1, const float* __restrict__ b1,
    const float* __restrict__ W2, const float* __restrict__ b2,
    const float* __restrict__ W3, const float* __restrict__ b3,
    const float* __restrict__ Wn, const float* __restrict__ Wr,
    const float* __restrict__ bg,
    __half* __restrict__ hWnOut, float* __restrict__ featP) {
    __shared__ float inL[68][8];
    __shared__ float h1[HH][8];
    __shared__ float h2[HH][8];
    __shared__ float hL[DD][8];
    const int c0 = blockIdx.x * 8;
    const int t  = threadIdx.x;

    for (int idx = t; idx < 8 * 68; idx += 128) {
        int ci = idx / 68, k = idx - ci * 68;
        inL[k][ci] = inAll[(c0 + ci) * 68 + k];   // coalesced read, scattered LDS write
    }
    __syncthreads();

    if (t < HH) {                            // stage 1: 68 -> 100, relu
        float acc[8];
        float bb = b1[t];
        #pragma unroll
        for (int ci = 0; ci < 8; ci++) acc[ci] = bb;
        for (int k = 0; k < 68; k++) {
            float w = W1[k * HH + t];
            FMA8(inL, k, w, acc);
        }
        STORE8_RELU(h1, t, acc);
    }
    __syncthreads();

    if (t < HH) {                            // stage 2: 100 -> 100, relu
        float acc[8];
        float bb = b2[t];
        #pragma unroll
        for (int ci = 0; ci < 8; ci++) acc[ci] = bb;
        for (int k = 0; k < HH; k++) {
            float w = W2[k * HH + t];
            FMA8(h1, k, w, acc);
        }
        STORE8_RELU(h2, t, acc);
    }
    __syncthreads();

    if (t < DD) {                            // stage 3: 100 -> 64 (no relu)
        float acc[8];
        float bb = b3[t];
        #pragma unroll
        for (int ci = 0; ci < 8; ci++) acc[ci] = bb;
        for (int k = 0; k < HH; k++) {
            float w = W3[k * DD + t];
            FMA8(h2, k, w, acc);
        }
        *(float4*)&hL[t][0] = make_float4(acc[0], acc[1], acc[2], acc[3]);
        *(float4*)&hL[t][4] = make_float4(acc[4], acc[5], acc[6], acc[7]);
    }
    __syncthreads();

    if (t < DD) {                            // stage 4: h@Wn (fp16) and h@Wr+bg
        float an[8], ar[8];
        float bgv = bg[t];
        #pragma unroll
        for (int ci = 0; ci < 8; ci++) { an[ci] = 0.0f; ar[ci] = bgv; }
        for (int k = 0; k < DD; k++) {
            float wn = Wn[k * DD + t];
            float wr = Wr[k * DD + t];
            float4 p = *(const float4*)&hL[k][0];
            float4 q = *(const float4*)&hL[k][4];
            an[0] += p.x * wn; ar[0] += p.x * wr;
            an[1] += p.y * wn; ar[1] += p.y * wr;
            an[2] += p.z * wn; ar[2] += p.z * wr;
            an[3] += p.w * wn; ar[3] += p.w * wr;
            an[4] += q.x * wn; ar[4] += q.x * wr;
            an[5] += q.y * wn; ar[5] += q.y * wr;
            an[6] += q.z * wn; ar[6] += q.z * wr;
            an[7] += q.w * wn; ar[7] += q.w * wr;
        }
        #pragma unroll
        for (int ci = 0; ci < 8; ci++) {
            hWnOut[(c0 + ci) * DD + t] = __float2half(an[ci]);
            featP [(c0 + ci) * DD + t] = ar[ci];
        }
    }
}

// ---------------------------------------------------------------------------
// K5a: horizontal 3-max of g[n] = hWn[cluster[n]] along image rows.
// One wave per 16-column chunk: ONE vector load of the 18 cluster ids
// (lanes 0..17), shfl-broadcast, 18 INDEPENDENT hWn row gathers (no chain),
// 16 fp16 row stores. Shares each gather across 3 window positions.
// ---------------------------------------------------------------------------
__global__ __launch_bounds__(256) void k_hmax(
    const int* __restrict__ cluster, const __half* __restrict__ hWn,
    __half* __restrict__ hmax) {
    const int w    = blockIdx.x * 4 + (threadIdx.x >> 6);   // 8192 waves
    const int lane = threadIdx.x & 63;
    const int b    = w >> 10;            // 1024 waves per image (128 rows x 8)
    const int rem  = w & 1023;
    const int i    = rem >> 3;
    const int j0   = (rem & 7) << 4;
    const int base = b * SS + i * SSZ;

    int jl  = j0 - 1 + lane;
    int cid = 0;
    if (lane < 18 && jl >= 0 && jl < SSZ) cid = cluster[base + jl];

    float val[18];
    #pragma unroll
    for (int p = 0; p < 18; p++) {
        int jp = j0 - 1 + p;
        int cp = __shfl(cid, p);
        if (jp >= 0 && jp < SSZ)
            val[p] = __half2float(hWn[(cp << 6) + lane]);
        else
            val[p] = -__builtin_inff();
    }

    const int outbase = (base + j0) << 6;
    #pragma unroll
    for (int k = 0; k < 16; k++) {
        float m = fmaxf(fmaxf(val[k], val[k + 1]), val[k + 2]);
        hmax[outbase + (k << 6) + lane] = __float2half(m);
    }
}

// ---------------------------------------------------------------------------
// K5b: vertical 3-max + per-cluster segment max, fused. One block (8 waves)
// per destination cluster; each member contributes max over hmax rows
// i-1..i+1 (3 independent 128B gathers from the L3-resident fp16 buffer).
// ---------------------------------------------------------------------------
__global__ __launch_bounds__(512) void k_vcmax(
    const int* __restrict__ binCnt, const int* __restrict__ nodeList,
    const __half* __restrict__ hmax, float* __restrict__ aggF) {
    __shared__ float pmx[8][64];
    const int wv = threadIdx.x >> 6, d = threadIdx.x & 63;
    const int c = blockIdx.x;
    int cnt = binCnt[c];
    if (cnt > BINCAP) cnt = BINCAP;
    float m = -__builtin_inff();
    for (int i = wv; i < cnt; i += 8) {
        int n = nodeList[c * BINCAP + i];    // wave-uniform
        int b = n >> 14;
        int p = n & (SS - 1);
        int ii = p >> 7, jj = p & 127;
        #pragma unroll
        for (int di = -1; di <= 1; di++) {
            int i2 = ii + di;
            if (i2 < 0 || i2 >= SSZ) continue;   // wave-uniform
            m = fmaxf(m, __half2float(hmax[((b * SS + i2 * SSZ + jj) << 6) + d]));
        }
    }
    pmx[wv][d] = m;
    __syncthreads();
    if (threadIdx.x < 64) {
        int t = threadIdx.x;
        float mm = pmx[0][t];
        #pragma unroll
        for (int w = 1; w < 8; w++) mm = fmaxf(mm, pmx[w][t]);
        aggF[c * 64 + t] = (cnt == 0) ? 0.0f : mm;   // empty segment -> 0
    }
}

// ---------------------------------------------------------------------------
// K6: per-cluster Q-MLP (64->100->100->100->18) -> jsf cols 0..17.
// Transposed LDS activations (see k_mlp1).
// ---------------------------------------------------------------------------
__global__ __launch_bounds__(128) void k_qmlp(
    const float* __restrict__ featP, const float* __restrict__ aggF,
    const float* __restrict__ Q1w, const float* __restrict__ Q1b,
    const float* __restrict__ Q2w, const float* __restrict__ Q2b,
    const float* __restrict__ Q3w, const float* __restrict__ Q3b,
    const float* __restrict__ Q4w, const float* __restrict__ Q4b,
    float* __restrict__ jsf) {
    __shared__ float fL[DD][8];
    __shared__ float h1[HH][8];
    __shared__ float h2[HH][8];
    const int c0 = blockIdx.x * 8;
    const int t  = threadIdx.x;

    for (int idx = t; idx < 8 * DD; idx += 128) {
        int ci = idx >> 6, k = idx & 63;
        int c = c0 + ci;
        fL[k][ci] = featP[c * 64 + k] + aggF[c * 64 + k];
    }
    __syncthreads();

    if (t < HH) {                            // Q1: 64 -> 100, relu
        float acc[8];
        float bb = Q1b[t];
        #pragma unroll
        for (int ci = 0; ci < 8; ci++) acc[ci] = bb;
        for (int k = 0; k < DD; k++) {
            float w = Q1w[k * HH + t];
            FMA8(fL, k, w, acc);
        }
        STORE8_RELU(h1, t, acc);
    }
    __syncthreads();

    if (t < HH) {                            // Q2: 100 -> 100, relu
        float acc[8];
        float bb = Q2b[t];
        #pragma unroll
        for (int ci = 0; ci < 8; ci++) acc[ci] = bb;
        for (int k = 0; k < HH; k++) {
            float w = Q2w[k * HH + t];
            FMA8(h1, k, w, acc);
        }
        STORE8_RELU(h2, t, acc);
    }
    __syncthreads();

    if (t < HH) {                            // Q3: 100 -> 100, relu (into h1)
        float acc[8];
        float bb = Q3b[t];
        #pragma unroll
        for (int ci = 0; ci < 8; ci++) acc[ci] = bb;
        for (int k = 0; k < HH; k++) {
            float w = Q3w[k * HH + t];
            FMA8(h2, k, w, acc);
        }
        __syncthreads();                     // h1 reused: wait for Q2 readers
        STORE8_RELU(h1, t, acc);
    } else {
        __syncthreads();
    }
    __syncthreads();

    if (t < 18) {                            // Q4: 100 -> 18
        float acc[8];
        float bb = Q4b[t];
        #pragma unroll
        for (int ci = 0; ci < 8; ci++) acc[ci] = bb;
        for (int k = 0; k < HH; k++) {
            float w = Q4w[k * 18 + t];
            FMA8(h1, k, w, acc);
        }
        #pragma unroll
        for (int ci = 0; ci < 8; ci++) jsf[(c0 + ci) * 20 + t] = acc[ci];
    }
}

// ---------------------------------------------------------------------------
// K7: per-node quadratic render
// ---------------------------------------------------------------------------
__global__ void k_render(const float* __restrict__ jsf, const int* __restrict__ cluster,
                         const float* __restrict__ coords, float* __restrict__ out) {
    int n = blockIdx.x * 256 + threadIdx.x;
    if (n >= NNODES) return;
    int c = cluster[n];
    const float* f = &jsf[c * 20];
    float gx = coords[n * 2 + 0], gy = coords[n * 2 + 1];
    float dx = gx - f[0];
    float dy = gy - f[1];
    #pragma unroll
    for (int r = 0; r < 3; r++) {
        float a   = f[2 + r * 6 + 0];
        float ah  = f[2 + r * 6 + 1];
        float aw  = f[2 + r * 6 + 2];
        float ahh = f[2 + r * 6 + 3];
        float aww = f[2 + r * 6 + 4];
        float ahw = f[2 + r * 6 + 5];
        out[n * 3 + r] = a + ah * dx + aw * dy + ahh * dx * dx + aww * dy * dy + ahw * dx * dy;
    }
}

// ---------------------------------------------------------------------------
extern "C" void kernel_launch(void* const* d_in, const int* in_sizes, int n_in,
                              void* d_out, int out_size, void* d_ws, size_t ws_size,
                              hipStream_t stream) {
    const float* x       = (const float*)d_in[0];
    const float* coords  = (const float*)d_in[1];
    const int*   cluster = (const int*)  d_in[2];
    // d_in[3], d_in[4]: edge_src/edge_dst — reconstructed analytically (L=1 stencil)
    const float* W1  = (const float*)d_in[5];
    const float* b1  = (const float*)d_in[6];
    const float* W2  = (const float*)d_in[7];
    const float* b2  = (const float*)d_in[8];
    const float* W3  = (const float*)d_in[9];
    const float* b3  = (const float*)d_in[10];
    const float* Wr  = (const float*)d_in[11];
    const float* Wn  = (const float*)d_in[12];
    const float* bg  = (const float*)d_in[13];
    const float* Q1w = (const float*)d_in[14];
    const float* Q1b = (const float*)d_in[15];
    const float* Q2w = (const float*)d_in[16];
    const float* Q2b = (const float*)d_in[17];
    const float* Q3w = (const float*)d_in[18];
    const float* Q3b = (const float*)d_in[19];
    const float* Q4w = (const float*)d_in[20];
    const float* Q4b = (const float*)d_in[21];
    float* out = (float*)d_out;

    // workspace layout (4-byte units, fp16 tail):
    // [binCnt M][nodeList M*64][inAll M*68][featP M*64][aggF M*64][jsf M*20]
    // [hWnH M*64 half][hmaxH N*64 half]   (~37 MB total)
    int*    binCnt   = (int*)d_ws;
    int*    nodeList = binCnt + MM;
    float*  inAll    = (float*)(nodeList + MM * BINCAP);
    float*  featP    = inAll + MM * 68;
    float*  aggF     = featP + MM * 64;
    float*  jsf      = aggF  + MM * 64;
    __half* hWnH     = (__half*)(jsf + MM * 20);
    __half* hmaxH    = hWnH + MM * 64;

    hipMemsetAsync(binCnt, 0, MM * sizeof(int), stream);
    k_scatter<<<(NNODES + 255) / 256, 256, 0, stream>>>(cluster, binCnt, nodeList);
    k_reduce <<<MM, 512, 0, stream>>>(x, coords, binCnt, nodeList, inAll, jsf);
    k_mlp1   <<<MM / 8, 128, 0, stream>>>(inAll, W1, b1, W2, b2, W3, b3, Wn, Wr, bg, hWnH, featP);
    k_hmax   <<<2048, 256, 0, stream>>>(cluster, hWnH, hmaxH);
    k_vcmax  <<<MM, 512, 0, stream>>>(binCnt, nodeList, hmaxH, aggF);
    k_qmlp   <<<MM / 8, 128, 0, stream>>>(featP, aggF, Q1w, Q1b, Q2w, Q2b, Q3w, Q3b, Q4w, Q4b, jsf);
    k_render <<<(NNODES + 255) / 256, 256, 0, stream>>>(jsf, cluster, coords, out);
}

// Round 6
// 227.354 us; speedup vs baseline: 1.5610x; 1.1619x over previous
//
#include <hip/hip_runtime.h>
#include <hip/hip_fp16.h>
#include <cmath>

#define SSZ    128
#define SS     (SSZ*SSZ)
#define NB     8
#define NNODES (NB*SS)   /* 131072 */
#define DD     64
#define MM     16384
#define HH     100
#define BINCAP 64        /* max nodes per cluster bin */
#define KP     136       /* LDS/weight row stride in halves: 2-way bank alias only */
#define WSLOT  (112*KP)  /* one transposed weight matrix slot (halves) */

typedef _Float16 f16x8 __attribute__((ext_vector_type(8)));
typedef float    f32x4 __attribute__((ext_vector_type(4)));

// ---------------------------------------------------------------------------
// K0: transpose+convert all weight matrices to fp16 [n][k], stride KP, zero-pad.
// Slots: 0:W1 1:W2 2:W3 3:Wn 4:Wr 5:Q1 6:Q2 7:Q3 8:Q4
// ---------------------------------------------------------------------------
__global__ void k_prep(const float* __restrict__ W1, const float* __restrict__ W2,
                       const float* __restrict__ W3, const float* __restrict__ Wn,
                       const float* __restrict__ Wr, const float* __restrict__ Q1w,
                       const float* __restrict__ Q2w, const float* __restrict__ Q3w,
                       const float* __restrict__ Q4w, __half* __restrict__ Wt) {
    int idx = blockIdx.x * 256 + threadIdx.x;
    if (idx >= 9 * WSLOT) return;
    int mat = idx / WSLOT, rem = idx - mat * WSLOT;
    int n = rem / KP, k = rem - n * KP;
    const float* src; int K, N;
    switch (mat) {
        case 0: src = W1;  K = 68;  N = 100; break;
        case 1: src = W2;  K = 100; N = 100; break;
        case 2: src = W3;  K = 100; N = 64;  break;
        case 3: src = Wn;  K = 64;  N = 64;  break;
        case 4: src = Wr;  K = 64;  N = 64;  break;
        case 5: src = Q1w; K = 64;  N = 100; break;
        case 6: src = Q2w; K = 100; N = 100; break;
        case 7: src = Q3w; K = 100; N = 100; break;
        default:src = Q4w; K = 100; N = 18;  break;
    }
    float v = (n < N && k < K) ? src[k * N + n] : 0.0f;
    Wt[idx] = __float2half(v);
}

// ---------------------------------------------------------------------------
// K2: bin nodes by cluster.
// ---------------------------------------------------------------------------
__global__ void k_scatter(const int* __restrict__ cluster,
                          int* __restrict__ binCnt, int* __restrict__ nodeList) {
    int n = blockIdx.x * 256 + threadIdx.x;
    if (n >= NNODES) return;
    int c = cluster[n];
    int pos = atomicAdd(&binCnt[c], 1);
    if (pos < BINCAP) nodeList[c * BINCAP + pos] = n;
}

// ---------------------------------------------------------------------------
// K3: per-cluster segment mean. One block (8 waves) per cluster.
// ---------------------------------------------------------------------------
__global__ __launch_bounds__(512) void k_reduce(
    const float* __restrict__ x, const float* __restrict__ coords,
    const int* __restrict__ binCnt, const int* __restrict__ nodeList,
    float* __restrict__ inAll, float* __restrict__ jsf) {
    __shared__ float px[8][64];
    __shared__ float pc[8][2];
    __shared__ float pm[8][2];
    const int wv = threadIdx.x >> 6, d = threadIdx.x & 63;
    const int c = blockIdx.x;
    int cnt = binCnt[c];
    if (cnt > BINCAP) cnt = BINCAP;
    float sx = 0.0f, sc = 0.0f, sm = 0.0f;
    for (int i = wv; i < cnt; i += 8) {
        int n = nodeList[c * BINCAP + i];
        sx += x[n * 64 + d];
        if (d < 2) { float cv = coords[n * 2 + d]; sc += cv; sm += cv * cv; }
    }
    px[wv][d] = sx;
    if (d < 2) { pc[wv][d] = sc; pm[wv][d] = sm; }
    __syncthreads();
    if (threadIdx.x < 64) {
        int t = threadIdx.x;
        float s = 0.0f;
        #pragma unroll
        for (int w = 0; w < 8; w++) s += px[w][t];
        float fcnt = fmaxf((float)cnt, 1.0f);
        inAll[c * 68 + t] = s / fcnt;
        if (t < 2) {
            float scs = 0.0f, sms = 0.0f;
            #pragma unroll
            for (int w = 0; w < 8; w++) { scs += pc[w][t]; sms += pm[w][t]; }
            float cent = scs / fcnt;
            inAll[c * 68 + 64 + t] = 10.0f * cent;
            inAll[c * 68 + 66 + t] = 10.0f * sms / fcnt;
            jsf[c * 20 + 18 + t] = cent;
        }
    }
}

// ---------------------------------------------------------------------------
// MFMA GEMM stage: C[16 x NT*16] = act(A[16 x K] * Wt^T + bias).
// Block = 16 clusters; 4 waves split N-tiles (t = w, w+4, ...).
// A-frags: ds_read_b128 from LDS row-major (stride KP).
// B-frags: 16B contiguous global loads from transposed fp16 weights.
// Layouts (m89/m91-verified): A[m=lane&15][k=q*8+j]; B[k=q*8+j][n=lane&15];
// C row=q*4+r, col=lane&15.
// ---------------------------------------------------------------------------
template<int KC, int NT>
__device__ __forceinline__ void mfma_stage(
    const _Float16* __restrict__ inBuf, _Float16* __restrict__ outBuf,
    const _Float16* __restrict__ Wt, const float* __restrict__ bias,
    int Nout, bool relu, int w, int lane) {
    const int m = lane & 15, q = lane >> 4;
    f16x8 a[KC];
    #pragma unroll
    for (int kc = 0; kc < KC; kc++)
        a[kc] = *(const f16x8*)&inBuf[m * KP + kc * 32 + q * 8];
    #pragma unroll
    for (int tt = 0; tt < (NT + 3) / 4; tt++) {
        const int t = w + tt * 4;
        if (t >= NT) break;                          // wave-uniform
        f32x4 acc = {0.0f, 0.0f, 0.0f, 0.0f};
        #pragma unroll
        for (int kc = 0; kc < KC; kc++) {
            f16x8 b = *(const f16x8*)&Wt[(16 * t + m) * KP + kc * 32 + q * 8];
            acc = __builtin_amdgcn_mfma_f32_16x16x32_f16(a[kc], b, acc, 0, 0, 0);
        }
        const int n = 16 * t + m;
        const float bb = (n < Nout) ? bias[n] : 0.0f;
        #pragma unroll
        for (int r = 0; r < 4; r++) {
            float c = acc[r] + bb;
            if (relu) c = fmaxf(c, 0.0f);
            if (n < Nout) outBuf[(q * 4 + r) * KP + n] = (_Float16)c;
        }
    }
}

// ---------------------------------------------------------------------------
// K4: MLP1 (68->100->100->64) + h@Wn (fp16) + h@Wr+bg, MFMA fp16.
// 16 clusters per block, 256 threads (4 waves).
// ---------------------------------------------------------------------------
__global__ __launch_bounds__(256) void k_mlp1(
    const float* __restrict__ inAll, const __half* __restrict__ WtAll,
    const float* __restrict__ b1, const float* __restrict__ b2,
    const float* __restrict__ b3, const float* __restrict__ bg,
    __half* __restrict__ hWnOut, float* __restrict__ featP) {
    __shared__ __align__(16) _Float16 sb0[16 * KP];
    __shared__ __align__(16) _Float16 sb1[16 * KP];
    const _Float16* Wt = (const _Float16*)WtAll;
    const int tid = threadIdx.x, lane = tid & 63, w = tid >> 6;
    const int c0 = blockIdx.x * 16;
    const int m = lane & 15, q = lane >> 4;

    // staging: A0 = inAll (16x68 fp32 -> fp16); zero pads (cols 68.. / 100..)
    for (int i = tid; i < 16 * 68; i += 256) {
        int r = i / 68, k = i - r * 68;
        sb0[r * KP + k] = (_Float16)inAll[(c0 + r) * 68 + k];
    }
    for (int i = tid; i < 16 * 68; i += 256) {       // sb0 cols 68..135 = 0
        int r = i / 68, k = 68 + (i - r * 68);
        sb0[r * KP + k] = (_Float16)0.0f;
    }
    for (int i = tid; i < 16 * 36; i += 256) {       // sb1 cols 100..135 = 0
        int r = i / 36, k = 100 + (i - r * 36);
        sb1[r * KP + k] = (_Float16)0.0f;
    }
    __syncthreads();

    mfma_stage<3, 7>(sb0, sb1, Wt + 0 * WSLOT, b1, 100, true,  w, lane);  // S1
    __syncthreads();
    mfma_stage<4, 7>(sb1, sb0, Wt + 1 * WSLOT, b2, 100, true,  w, lane);  // S2
    __syncthreads();
    mfma_stage<4, 4>(sb0, sb1, Wt + 2 * WSLOT, b3, 64,  false, w, lane);  // S3
    __syncthreads();

    // S4/S5: hWn = H3 @ Wn (fp16 out), featP = H3 @ Wr + bg. N=64: tile t = w.
    {
        const _Float16* Wnt = Wt + 3 * WSLOT;
        const _Float16* Wrt = Wt + 4 * WSLOT;
        f16x8 a0 = *(const f16x8*)&sb1[m * KP + q * 8];
        f16x8 a1 = *(const f16x8*)&sb1[m * KP + 32 + q * 8];
        const int t = w;
        f16x8 bn0 = *(const f16x8*)&Wnt[(16 * t + m) * KP + q * 8];
        f16x8 bn1 = *(const f16x8*)&Wnt[(16 * t + m) * KP + 32 + q * 8];
        f16x8 br0 = *(const f16x8*)&Wrt[(16 * t + m) * KP + q * 8];
        f16x8 br1 = *(const f16x8*)&Wrt[(16 * t + m) * KP + 32 + q * 8];
        f32x4 an = {0.0f, 0.0f, 0.0f, 0.0f};
        f32x4 ar = {0.0f, 0.0f, 0.0f, 0.0f};
        an = __builtin_amdgcn_mfma_f32_16x16x32_f16(a0, bn0, an, 0, 0, 0);
        an = __builtin_amdgcn_mfma_f32_16x16x32_f16(a1, bn1, an, 0, 0, 0);
        ar = __builtin_amdgcn_mfma_f32_16x16x32_f16(a0, br0, ar, 0, 0, 0);
        ar = __builtin_amdgcn_mfma_f32_16x16x32_f16(a1, br1, ar, 0, 0, 0);
        const int n = 16 * t + m;
        const float bgv = bg[n];
        #pragma unroll
        for (int r = 0; r < 4; r++) {
            int row = c0 + q * 4 + r;
            hWnOut[row * 64 + n] = __float2half(an[r]);
            featP [row * 64 + n] = ar[r] + bgv;
        }
    }
}

// ---------------------------------------------------------------------------
// K5a: horizontal 3-max of g[n] = hWn[cluster[n]] along image rows.
// ---------------------------------------------------------------------------
__global__ __launch_bounds__(256) void k_hmax(
    const int* __restrict__ cluster, const __half* __restrict__ hWn,
    __half* __restrict__ hmax) {
    const int w    = blockIdx.x * 4 + (threadIdx.x >> 6);   // 8192 waves
    const int lane = threadIdx.x & 63;
    const int b    = w >> 10;
    const int rem  = w & 1023;
    const int i    = rem >> 3;
    const int j0   = (rem & 7) << 4;
    const int base = b * SS + i * SSZ;

    int jl  = j0 - 1 + lane;
    int cid = 0;
    if (lane < 18 && jl >= 0 && jl < SSZ) cid = cluster[base + jl];

    float val[18];
    #pragma unroll
    for (int p = 0; p < 18; p++) {
        int jp = j0 - 1 + p;
        int cp = __shfl(cid, p);
        if (jp >= 0 && jp < SSZ)
            val[p] = __half2float(hWn[(cp << 6) + lane]);
        else
            val[p] = -__builtin_inff();
    }

    const int outbase = (base + j0) << 6;
    #pragma unroll
    for (int k = 0; k < 16; k++) {
        float m = fmaxf(fmaxf(val[k], val[k + 1]), val[k + 2]);
        hmax[outbase + (k << 6) + lane] = __float2half(m);
    }
}

// ---------------------------------------------------------------------------
// K5b: vertical 3-max + per-cluster segment max, fused.
// ---------------------------------------------------------------------------
__global__ __launch_bounds__(512) void k_vcmax(
    const int* __restrict__ binCnt, const int* __restrict__ nodeList,
    const __half* __restrict__ hmax, float* __restrict__ aggF) {
    __shared__ float pmx[8][64];
    const int wv = threadIdx.x >> 6, d = threadIdx.x & 63;
    const int c = blockIdx.x;
    int cnt = binCnt[c];
    if (cnt > BINCAP) cnt = BINCAP;
    float m = -__builtin_inff();
    for (int i = wv; i < cnt; i += 8) {
        int n = nodeList[c * BINCAP + i];    // wave-uniform
        int b = n >> 14;
        int p = n & (SS - 1);
        int ii = p >> 7, jj = p & 127;
        #pragma unroll
        for (int di = -1; di <= 1; di++) {
            int i2 = ii + di;
            if (i2 < 0 || i2 >= SSZ) continue;   // wave-uniform
            m = fmaxf(m, __half2float(hmax[((b * SS + i2 * SSZ + jj) << 6) + d]));
        }
    }
    pmx[wv][d] = m;
    __syncthreads();
    if (threadIdx.x < 64) {
        int t = threadIdx.x;
        float mm = pmx[0][t];
        #pragma unroll
        for (int w = 1; w < 8; w++) mm = fmaxf(mm, pmx[w][t]);
        aggF[c * 64 + t] = (cnt == 0) ? 0.0f : mm;   // empty segment -> 0
    }
}

// ---------------------------------------------------------------------------
// K6: Q-MLP (64->100->100->100->18), MFMA fp16. 16 clusters/block, 4 waves.
// ---------------------------------------------------------------------------
__global__ __launch_bounds__(256) void k_qmlp(
    const float* __restrict__ featP, const float* __restrict__ aggF,
    const __half* __restrict__ WtAll,
    const float* __restrict__ Q1b, const float* __restrict__ Q2b,
    const float* __restrict__ Q3b, const float* __restrict__ Q4b,
    float* __restrict__ jsf) {
    __shared__ __align__(16) _Float16 sb0[16 * KP];
    __shared__ __align__(16) _Float16 sb1[16 * KP];
    const _Float16* Wt = (const _Float16*)WtAll;
    const int tid = threadIdx.x, lane = tid & 63, w = tid >> 6;
    const int c0 = blockIdx.x * 16;
    const int m = lane & 15, q = lane >> 4;

    // staging: A0 = featP + aggF (16x64), zero pads for K=100 reads later
    for (int i = tid; i < 16 * 64; i += 256) {
        int r = i >> 6, k = i & 63;
        int g = (c0 + r) * 64 + k;
        sb0[r * KP + k] = (_Float16)(featP[g] + aggF[g]);
    }
    for (int i = tid; i < 16 * 36; i += 256) {       // sb0 cols 100..135 = 0
        int r = i / 36, k = 100 + (i - r * 36);
        sb0[r * KP + k] = (_Float16)0.0f;
    }
    for (int i = tid; i < 16 * 36; i += 256) {       // sb1 cols 100..135 = 0
        int r = i / 36, k = 100 + (i - r * 36);
        sb1[r * KP + k] = (_Float16)0.0f;
    }
    __syncthreads();

    mfma_stage<2, 7>(sb0, sb1, Wt + 5 * WSLOT, Q1b, 100, true, w, lane);  // Q1
    __syncthreads();
    mfma_stage<4, 7>(sb1, sb0, Wt + 6 * WSLOT, Q2b, 100, true, w, lane);  // Q2
    __syncthreads();
    mfma_stage<4, 7>(sb0, sb1, Wt + 7 * WSLOT, Q3b, 100, true, w, lane);  // Q3
    __syncthreads();

    // Q4: K=100 (KC=4), N=18 (2 tiles: waves 0,1) -> global jsf
    if (w < 2) {
        const _Float16* Q4t = Wt + 8 * WSLOT;
        f16x8 a[4];
        #pragma unroll
        for (int kc = 0; kc < 4; kc++)
            a[kc] = *(const f16x8*)&sb1[m * KP + kc * 32 + q * 8];
        const int t = w;
        f32x4 acc = {0.0f, 0.0f, 0.0f, 0.0f};
        #pragma unroll
        for (int kc = 0; kc < 4; kc++) {
            f16x8 b = *(const f16x8*)&Q4t[(16 * t + m) * KP + kc * 32 + q * 8];
            acc = __builtin_amdgcn_mfma_f32_16x16x32_f16(a[kc], b, acc, 0, 0, 0);
        }
        const int n = 16 * t + m;
        if (n < 18) {
            const float bb = Q4b[n];
            #pragma unroll
            for (int r = 0; r < 4; r++)
                jsf[(c0 + q * 4 + r) * 20 + n] = acc[r] + bb;
        }
    }
}

// ---------------------------------------------------------------------------
// K7: per-node quadratic render
// ---------------------------------------------------------------------------
__global__ void k_render(const float* __restrict__ jsf, const int* __restrict__ cluster,
                         const float* __restrict__ coords, float* __restrict__ out) {
    int n = blockIdx.x * 256 + threadIdx.x;
    if (n >= NNODES) return;
    int c = cluster[n];
    const float* f = &jsf[c * 20];
    float gx = coords[n * 2 + 0], gy = coords[n * 2 + 1];
    float dx = gx - f[0];
    float dy = gy - f[1];
    #pragma unroll
    for (int r = 0; r < 3; r++) {
        float a   = f[2 + r * 6 + 0];
        float ah  = f[2 + r * 6 + 1];
        float aw  = f[2 + r * 6 + 2];
        float ahh = f[2 + r * 6 + 3];
        float aww = f[2 + r * 6 + 4];
        float ahw = f[2 + r * 6 + 5];
        out[n * 3 + r] = a + ah * dx + aw * dy + ahh * dx * dx + aww * dy * dy + ahw * dx * dy;
    }
}

// ---------------------------------------------------------------------------
extern "C" void kernel_launch(void* const* d_in, const int* in_sizes, int n_in,
                              void* d_out, int out_size, void* d_ws, size_t ws_size,
                              hipStream_t stream) {
    const float* x       = (const float*)d_in[0];
    const float* coords  = (const float*)d_in[1];
    const int*   cluster = (const int*)  d_in[2];
    // d_in[3], d_in[4]: edge_src/edge_dst — reconstructed analytically (L=1 stencil)
    const float* W1  = (const float*)d_in[5];
    const float* b1  = (const float*)d_in[6];
    const float* W2  = (const float*)d_in[7];
    const float* b2  = (const float*)d_in[8];
    const float* W3  = (const float*)d_in[9];
    const float* b3  = (const float*)d_in[10];
    const float* Wr  = (const float*)d_in[11];
    const float* Wn  = (const float*)d_in[12];
    const float* bg  = (const float*)d_in[13];
    const float* Q1w = (const float*)d_in[14];
    const float* Q1b = (const float*)d_in[15];
    const float* Q2w = (const float*)d_in[16];
    const float* Q2b = (const float*)d_in[17];
    const float* Q3w = (const float*)d_in[18];
    const float* Q3b = (const float*)d_in[19];
    const float* Q4w = (const float*)d_in[20];
    const float* Q4b = (const float*)d_in[21];
    float* out = (float*)d_out;

    // workspace layout (4-byte units, fp16 tail):
    // [binCnt M][nodeList M*64][inAll M*68][featP M*64][aggF M*64][jsf M*20]
    // [hWnH M*64 h][hmaxH N*64 h][WtH 9*WSLOT h]
    int*    binCnt   = (int*)d_ws;
    int*    nodeList = binCnt + MM;
    float*  inAll    = (float*)(nodeList + MM * BINCAP);
    float*  featP    = inAll + MM * 68;
    float*  aggF     = featP + MM * 64;
    float*  jsf      = aggF  + MM * 64;
    __half* hWnH     = (__half*)(jsf + MM * 20);
    __half* hmaxH    = hWnH + MM * 64;
    __half* WtH      = hmaxH + (size_t)NNODES * 64;

    hipMemsetAsync(binCnt, 0, MM * sizeof(int), stream);
    k_prep   <<<(9 * WSLOT + 255) / 256, 256, 0, stream>>>(W1, W2, W3, Wn, Wr,
                                                           Q1w, Q2w, Q3w, Q4w, WtH);
    k_scatter<<<(NNODES + 255) / 256, 256, 0, stream>>>(cluster, binCnt, nodeList);
    k_reduce <<<MM, 512, 0, stream>>>(x, coords, binCnt, nodeList, inAll, jsf);
    k_mlp1   <<<MM / 16, 256, 0, stream>>>(inAll, WtH, b1, b2, b3, bg, hWnH, featP);
    k_hmax   <<<2048, 256, 0, stream>>>(cluster, hWnH, hmaxH);
    k_vcmax  <<<MM, 512, 0, stream>>>(binCnt, nodeList, hmaxH, aggF);
    k_qmlp   <<<MM / 16, 256, 0, stream>>>(featP, aggF, WtH, Q1b, Q2b, Q3b, Q4b, jsf);
    k_render <<<(NNODES + 255) / 256, 256, 0, stream>>>(jsf, cluster, coords, out);
}

// Round 7
// 211.946 us; speedup vs baseline: 1.6745x; 1.0727x over previous
//
#include <hip/hip_runtime.h>
#include <hip/hip_fp16.h>
#include <cmath>

#define SSZ    128
#define SS     (SSZ*SSZ)
#define NB     8
#define NNODES (NB*SS)   /* 131072 */
#define DD     64
#define MM     16384
#define HH     100
#define BINCAP 64        /* max nodes per cluster bin */
#define KP     136       /* LDS/weight row stride in halves: 2-way bank alias only */
#define WSLOT  (112*KP)  /* one transposed weight matrix slot (halves) */

typedef _Float16 f16x8 __attribute__((ext_vector_type(8)));
typedef float    f32x4 __attribute__((ext_vector_type(4)));

// ---------------------------------------------------------------------------
// K0: transpose+convert all weight matrices to fp16 [n][k], stride KP, zero-pad.
// Slots: 0:W1 1:W2 2:W3 3:Wn 4:Wr 5:Q1 6:Q2 7:Q3 8:Q4
// ---------------------------------------------------------------------------
__global__ void k_prep(const float* __restrict__ W1, const float* __restrict__ W2,
                       const float* __restrict__ W3, const float* __restrict__ Wn,
                       const float* __restrict__ Wr, const float* __restrict__ Q1w,
                       const float* __restrict__ Q2w, const float* __restrict__ Q3w,
                       const float* __restrict__ Q4w, __half* __restrict__ Wt) {
    int idx = blockIdx.x * 256 + threadIdx.x;
    if (idx >= 9 * WSLOT) return;
    int mat = idx / WSLOT, rem = idx - mat * WSLOT;
    int n = rem / KP, k = rem - n * KP;
    const float* src; int K, N;
    switch (mat) {
        case 0: src = W1;  K = 68;  N = 100; break;
        case 1: src = W2;  K = 100; N = 100; break;
        case 2: src = W3;  K = 100; N = 64;  break;
        case 3: src = Wn;  K = 64;  N = 64;  break;
        case 4: src = Wr;  K = 64;  N = 64;  break;
        case 5: src = Q1w; K = 64;  N = 100; break;
        case 6: src = Q2w; K = 100; N = 100; break;
        case 7: src = Q3w; K = 100; N = 100; break;
        default:src = Q4w; K = 100; N = 18;  break;
    }
    float v = (n < N && k < K) ? src[k * N + n] : 0.0f;
    Wt[idx] = __float2half(v);
}

// ---------------------------------------------------------------------------
// K2: bin nodes by cluster.
// ---------------------------------------------------------------------------
__global__ void k_scatter(const int* __restrict__ cluster,
                          int* __restrict__ binCnt, int* __restrict__ nodeList) {
    int n = blockIdx.x * 256 + threadIdx.x;
    if (n >= NNODES) return;
    int c = cluster[n];
    int pos = atomicAdd(&binCnt[c], 1);
    if (pos < BINCAP) nodeList[c * BINCAP + pos] = n;
}

// ---------------------------------------------------------------------------
// K3: per-cluster segment mean. One block (8 waves) per cluster.
// ---------------------------------------------------------------------------
__global__ __launch_bounds__(512) void k_reduce(
    const float* __restrict__ x, const float* __restrict__ coords,
    const int* __restrict__ binCnt, const int* __restrict__ nodeList,
    float* __restrict__ inAll, float* __restrict__ jsf) {
    __shared__ float px[8][64];
    __shared__ float pc[8][2];
    __shared__ float pm[8][2];
    const int wv = threadIdx.x >> 6, d = threadIdx.x & 63;
    const int c = blockIdx.x;
    int cnt = binCnt[c];
    if (cnt > BINCAP) cnt = BINCAP;
    float sx = 0.0f, sc = 0.0f, sm = 0.0f;
    for (int i = wv; i < cnt; i += 8) {
        int n = nodeList[c * BINCAP + i];
        sx += x[n * 64 + d];
        if (d < 2) { float cv = coords[n * 2 + d]; sc += cv; sm += cv * cv; }
    }
    px[wv][d] = sx;
    if (d < 2) { pc[wv][d] = sc; pm[wv][d] = sm; }
    __syncthreads();
    if (threadIdx.x < 64) {
        int t = threadIdx.x;
        float s = 0.0f;
        #pragma unroll
        for (int w = 0; w < 8; w++) s += px[w][t];
        float fcnt = fmaxf((float)cnt, 1.0f);
        inAll[c * 68 + t] = s / fcnt;
        if (t < 2) {
            float scs = 0.0f, sms = 0.0f;
            #pragma unroll
            for (int w = 0; w < 8; w++) { scs += pc[w][t]; sms += pm[w][t]; }
            float cent = scs / fcnt;
            inAll[c * 68 + 64 + t] = 10.0f * cent;
            inAll[c * 68 + 66 + t] = 10.0f * sms / fcnt;
            jsf[c * 20 + 18 + t] = cent;
        }
    }
}

// ---------------------------------------------------------------------------
// MFMA GEMM stage (m89/m91-verified fragment layouts).
// ---------------------------------------------------------------------------
template<int KC, int NT>
__device__ __forceinline__ void mfma_stage(
    const _Float16* __restrict__ inBuf, _Float16* __restrict__ outBuf,
    const _Float16* __restrict__ Wt, const float* __restrict__ bias,
    int Nout, bool relu, int w, int lane) {
    const int m = lane & 15, q = lane >> 4;
    f16x8 a[KC];
    #pragma unroll
    for (int kc = 0; kc < KC; kc++)
        a[kc] = *(const f16x8*)&inBuf[m * KP + kc * 32 + q * 8];
    #pragma unroll
    for (int tt = 0; tt < (NT + 3) / 4; tt++) {
        const int t = w + tt * 4;
        if (t >= NT) break;                          // wave-uniform
        f32x4 acc = {0.0f, 0.0f, 0.0f, 0.0f};
        #pragma unroll
        for (int kc = 0; kc < KC; kc++) {
            f16x8 b = *(const f16x8*)&Wt[(16 * t + m) * KP + kc * 32 + q * 8];
            acc = __builtin_amdgcn_mfma_f32_16x16x32_f16(a[kc], b, acc, 0, 0, 0);
        }
        const int n = 16 * t + m;
        const float bb = (n < Nout) ? bias[n] : 0.0f;
        #pragma unroll
        for (int r = 0; r < 4; r++) {
            float c = acc[r] + bb;
            if (relu) c = fmaxf(c, 0.0f);
            if (n < Nout) outBuf[(q * 4 + r) * KP + n] = (_Float16)c;
        }
    }
}

// ---------------------------------------------------------------------------
// K4: MLP1 (68->100->100->64) + h@Wn (fp16) + h@Wr+bg, MFMA fp16.
// ---------------------------------------------------------------------------
__global__ __launch_bounds__(256) void k_mlp1(
    const float* __restrict__ inAll, const __half* __restrict__ WtAll,
    const float* __restrict__ b1, const float* __restrict__ b2,
    const float* __restrict__ b3, const float* __restrict__ bg,
    __half* __restrict__ hWnOut, float* __restrict__ featP) {
    __shared__ __align__(16) _Float16 sb0[16 * KP];
    __shared__ __align__(16) _Float16 sb1[16 * KP];
    const _Float16* Wt = (const _Float16*)WtAll;
    const int tid = threadIdx.x, lane = tid & 63, w = tid >> 6;
    const int c0 = blockIdx.x * 16;
    const int m = lane & 15, q = lane >> 4;

    for (int i = tid; i < 16 * 68; i += 256) {
        int r = i / 68, k = i - r * 68;
        sb0[r * KP + k] = (_Float16)inAll[(c0 + r) * 68 + k];
    }
    for (int i = tid; i < 16 * 68; i += 256) {       // sb0 cols 68..135 = 0
        int r = i / 68, k = 68 + (i - r * 68);
        sb0[r * KP + k] = (_Float16)0.0f;
    }
    for (int i = tid; i < 16 * 36; i += 256) {       // sb1 cols 100..135 = 0
        int r = i / 36, k = 100 + (i - r * 36);
        sb1[r * KP + k] = (_Float16)0.0f;
    }
    __syncthreads();

    mfma_stage<3, 7>(sb0, sb1, Wt + 0 * WSLOT, b1, 100, true,  w, lane);  // S1
    __syncthreads();
    mfma_stage<4, 7>(sb1, sb0, Wt + 1 * WSLOT, b2, 100, true,  w, lane);  // S2
    __syncthreads();
    mfma_stage<4, 4>(sb0, sb1, Wt + 2 * WSLOT, b3, 64,  false, w, lane);  // S3
    __syncthreads();

    {   // S4/S5: hWn = H3 @ Wn (fp16 out), featP = H3 @ Wr + bg
        const _Float16* Wnt = Wt + 3 * WSLOT;
        const _Float16* Wrt = Wt + 4 * WSLOT;
        f16x8 a0 = *(const f16x8*)&sb1[m * KP + q * 8];
        f16x8 a1 = *(const f16x8*)&sb1[m * KP + 32 + q * 8];
        const int t = w;
        f16x8 bn0 = *(const f16x8*)&Wnt[(16 * t + m) * KP + q * 8];
        f16x8 bn1 = *(const f16x8*)&Wnt[(16 * t + m) * KP + 32 + q * 8];
        f16x8 br0 = *(const f16x8*)&Wrt[(16 * t + m) * KP + q * 8];
        f16x8 br1 = *(const f16x8*)&Wrt[(16 * t + m) * KP + 32 + q * 8];
        f32x4 an = {0.0f, 0.0f, 0.0f, 0.0f};
        f32x4 ar = {0.0f, 0.0f, 0.0f, 0.0f};
        an = __builtin_amdgcn_mfma_f32_16x16x32_f16(a0, bn0, an, 0, 0, 0);
        an = __builtin_amdgcn_mfma_f32_16x16x32_f16(a1, bn1, an, 0, 0, 0);
        ar = __builtin_amdgcn_mfma_f32_16x16x32_f16(a0, br0, ar, 0, 0, 0);
        ar = __builtin_amdgcn_mfma_f32_16x16x32_f16(a1, br1, ar, 0, 0, 0);
        const int n = 16 * t + m;
        const float bgv = bg[n];
        #pragma unroll
        for (int r = 0; r < 4; r++) {
            int row = c0 + q * 4 + r;
            hWnOut[row * 64 + n] = __float2half(an[r]);
            featP [row * 64 + n] = ar[r] + bgv;
        }
    }
}

// ---------------------------------------------------------------------------
// K5: fused horizontal+vertical 3x3 max. One block per (8-row band x 16-col
// chunk): 8 waves build 10 hmax rows in LDS (gathers hit the L2-resident
// 2 MB hWn), then each wave emits one vmax row coalesced. hmax never
// touches HBM.
// ---------------------------------------------------------------------------
__global__ __launch_bounds__(512) void k_hvmax(
    const int* __restrict__ cluster, const __half* __restrict__ hWn,
    __half* __restrict__ vmax) {
    __shared__ __half hm[10][16][64];
    const int w = threadIdx.x >> 6, lane = threadIdx.x & 63;
    const int blk  = blockIdx.x;                 // 1024 blocks
    const int b    = blk >> 7;                   // image
    const int rem  = blk & 127;
    const int r0   = (rem >> 3) << 3;            // band start row
    const int j0   = (rem & 7) << 4;             // chunk start col
    const int base = b * SS;

    // lds row lr <-> global row r0-1+lr, lr in [0,10)
    for (int lr = w; lr < 10; lr += 8) {
        int gi = r0 - 1 + lr;
        if (gi < 0 || gi >= SSZ) {
            #pragma unroll
            for (int k = 0; k < 16; k++)
                hm[lr][k][lane] = __float2half(-__builtin_inff());
        } else {
            int rowbase = base + gi * SSZ;
            int jl = j0 - 1 + lane;
            int cid = 0;
            if (lane < 18 && jl >= 0 && jl < SSZ) cid = cluster[rowbase + jl];
            float val[18];
            #pragma unroll
            for (int p = 0; p < 18; p++) {
                int jp = j0 - 1 + p;
                int cp = __shfl(cid, p);
                val[p] = (jp >= 0 && jp < SSZ)
                       ? __half2float(hWn[(cp << 6) + lane])
                       : -__builtin_inff();
            }
            #pragma unroll
            for (int k = 0; k < 16; k++)
                hm[lr][k][lane] =
                    __float2half(fmaxf(fmaxf(val[k], val[k + 1]), val[k + 2]));
        }
    }
    __syncthreads();

    // wave w -> output row r0+w from lds rows w, w+1, w+2
    const int outbase = (base + (r0 + w) * SSZ + j0) << 6;
    #pragma unroll
    for (int k = 0; k < 16; k++) {
        float v = fmaxf(fmaxf(__half2float(hm[w][k][lane]),
                              __half2float(hm[w + 1][k][lane])),
                        __half2float(hm[w + 2][k][lane]));
        vmax[outbase + (k << 6) + lane] = __float2half(v);
    }
}

// ---------------------------------------------------------------------------
// K5b: per-cluster segment max over members' vmax rows — ONE 128B gather per
// member (was 3). One block (8 waves) per cluster, LDS combine.
// ---------------------------------------------------------------------------
__global__ __launch_bounds__(512) void k_cmax(
    const int* __restrict__ binCnt, const int* __restrict__ nodeList,
    const __half* __restrict__ vmax, float* __restrict__ aggF) {
    __shared__ float pmx[8][64];
    const int wv = threadIdx.x >> 6, d = threadIdx.x & 63;
    const int c = blockIdx.x;
    int cnt = binCnt[c];
    if (cnt > BINCAP) cnt = BINCAP;
    float m = -__builtin_inff();
    for (int i = wv; i < cnt; i += 8) {
        int n = nodeList[c * BINCAP + i];    // wave-uniform
        m = fmaxf(m, __half2float(vmax[(n << 6) + d]));
    }
    pmx[wv][d] = m;
    __syncthreads();
    if (threadIdx.x < 64) {
        int t = threadIdx.x;
        float mm = pmx[0][t];
        #pragma unroll
        for (int w = 1; w < 8; w++) mm = fmaxf(mm, pmx[w][t]);
        aggF[c * 64 + t] = (cnt == 0) ? 0.0f : mm;   // empty segment -> 0
    }
}

// ---------------------------------------------------------------------------
// K6: Q-MLP (64->100->100->100->18), MFMA fp16.
// ---------------------------------------------------------------------------
__global__ __launch_bounds__(256) void k_qmlp(
    const float* __restrict__ featP, const float* __restrict__ aggF,
    const __half* __restrict__ WtAll,
    const float* __restrict__ Q1b, const float* __restrict__ Q2b,
    const float* __restrict__ Q3b, const float* __restrict__ Q4b,
    float* __restrict__ jsf) {
    __shared__ __align__(16) _Float16 sb0[16 * KP];
    __shared__ __align__(16) _Float16 sb1[16 * KP];
    const _Float16* Wt = (const _Float16*)WtAll;
    const int tid = threadIdx.x, lane = tid & 63, w = tid >> 6;
    const int c0 = blockIdx.x * 16;
    const int m = lane & 15, q = lane >> 4;

    for (int i = tid; i < 16 * 64; i += 256) {
        int r = i >> 6, k = i & 63;
        int g = (c0 + r) * 64 + k;
        sb0[r * KP + k] = (_Float16)(featP[g] + aggF[g]);
    }
    for (int i = tid; i < 16 * 36; i += 256) {       // sb0 cols 100..135 = 0
        int r = i / 36, k = 100 + (i - r * 36);
        sb0[r * KP + k] = (_Float16)0.0f;
    }
    for (int i = tid; i < 16 * 36; i += 256) {       // sb1 cols 100..135 = 0
        int r = i / 36, k = 100 + (i - r * 36);
        sb1[r * KP + k] = (_Float16)0.0f;
    }
    __syncthreads();

    mfma_stage<2, 7>(sb0, sb1, Wt + 5 * WSLOT, Q1b, 100, true, w, lane);  // Q1
    __syncthreads();
    mfma_stage<4, 7>(sb1, sb0, Wt + 6 * WSLOT, Q2b, 100, true, w, lane);  // Q2
    __syncthreads();
    mfma_stage<4, 7>(sb0, sb1, Wt + 7 * WSLOT, Q3b, 100, true, w, lane);  // Q3
    __syncthreads();

    if (w < 2) {                                     // Q4: K=100, N=18
        const _Float16* Q4t = Wt + 8 * WSLOT;
        f16x8 a[4];
        #pragma unroll
        for (int kc = 0; kc < 4; kc++)
            a[kc] = *(const f16x8*)&sb1[m * KP + kc * 32 + q * 8];
        const int t = w;
        f32x4 acc = {0.0f, 0.0f, 0.0f, 0.0f};
        #pragma unroll
        for (int kc = 0; kc < 4; kc++) {
            f16x8 b = *(const f16x8*)&Q4t[(16 * t + m) * KP + kc * 32 + q * 8];
            acc = __builtin_amdgcn_mfma_f32_16x16x32_f16(a[kc], b, acc, 0, 0, 0);
        }
        const int n = 16 * t + m;
        if (n < 18) {
            const float bb = Q4b[n];
            #pragma unroll
            for (int r = 0; r < 4; r++)
                jsf[(c0 + q * 4 + r) * 20 + n] = acc[r] + bb;
        }
    }
}

// ---------------------------------------------------------------------------
// K7: per-node quadratic render
// ---------------------------------------------------------------------------
__global__ void k_render(const float* __restrict__ jsf, const int* __restrict__ cluster,
                         const float* __restrict__ coords, float* __restrict__ out) {
    int n = blockIdx.x * 256 + threadIdx.x;
    if (n >= NNODES) return;
    int c = cluster[n];
    const float* f = &jsf[c * 20];
    float gx = coords[n * 2 + 0], gy = coords[n * 2 + 1];
    float dx = gx - f[0];
    float dy = gy - f[1];
    #pragma unroll
    for (int r = 0; r < 3; r++) {
        float a   = f[2 + r * 6 + 0];
        float ah  = f[2 + r * 6 + 1];
        float aw  = f[2 + r * 6 + 2];
        float ahh = f[2 + r * 6 + 3];
        float aww = f[2 + r * 6 + 4];
        float ahw = f[2 + r * 6 + 5];
        out[n * 3 + r] = a + ah * dx + aw * dy + ahh * dx * dx + aww * dy * dy + ahw * dx * dy;
    }
}

// ---------------------------------------------------------------------------
extern "C" void kernel_launch(void* const* d_in, const int* in_sizes, int n_in,
                              void* d_out, int out_size, void* d_ws, size_t ws_size,
                              hipStream_t stream) {
    const float* x       = (const float*)d_in[0];
    const float* coords  = (const float*)d_in[1];
    const int*   cluster = (const int*)  d_in[2];
    // d_in[3], d_in[4]: edge_src/edge_dst — reconstructed analytically (L=1 stencil)
    const float* W1  = (const float*)d_in[5];
    const float* b1  = (const float*)d_in[6];
    const float* W2  = (const float*)d_in[7];
    const float* b2  = (const float*)d_in[8];
    const float* W3  = (const float*)d_in[9];
    const float* b3  = (const float*)d_in[10];
    const float* Wr  = (const float*)d_in[11];
    const float* Wn  = (const float*)d_in[12];
    const float* bg  = (const float*)d_in[13];
    const float* Q1w = (const float*)d_in[14];
    const float* Q1b = (const float*)d_in[15];
    const float* Q2w = (const float*)d_in[16];
    const float* Q2b = (const float*)d_in[17];
    const float* Q3w = (const float*)d_in[18];
    const float* Q3b = (const float*)d_in[19];
    const float* Q4w = (const float*)d_in[20];
    const float* Q4b = (const float*)d_in[21];
    float* out = (float*)d_out;

    // workspace layout (4-byte units, fp16 tail):
    // [binCnt M][nodeList M*64][inAll M*68][featP M*64][aggF M*64][jsf M*20]
    // [hWnH M*64 h][vmaxH N*64 h][WtH 9*WSLOT h]
    int*    binCnt   = (int*)d_ws;
    int*    nodeList = binCnt + MM;
    float*  inAll    = (float*)(nodeList + MM * BINCAP);
    float*  featP    = inAll + MM * 68;
    float*  aggF     = featP + MM * 64;
    float*  jsf      = aggF  + MM * 64;
    __half* hWnH     = (__half*)(jsf + MM * 20);
    __half* vmaxH    = hWnH + MM * 64;
    __half* WtH      = vmaxH + (size_t)NNODES * 64;

    hipMemsetAsync(binCnt, 0, MM * sizeof(int), stream);
    k_prep   <<<(9 * WSLOT + 255) / 256, 256, 0, stream>>>(W1, W2, W3, Wn, Wr,
                                                           Q1w, Q2w, Q3w, Q4w, WtH);
    k_scatter<<<(NNODES + 255) / 256, 256, 0, stream>>>(cluster, binCnt, nodeList);
    k_reduce <<<MM, 512, 0, stream>>>(x, coords, binCnt, nodeList, inAll, jsf);
    k_mlp1   <<<MM / 16, 256, 0, stream>>>(inAll, WtH, b1, b2, b3, bg, hWnH, featP);
    k_hvmax  <<<1024, 512, 0, stream>>>(cluster, hWnH, vmaxH);
    k_cmax   <<<MM, 512, 0, stream>>>(binCnt, nodeList, vmaxH, aggF);
    k_qmlp   <<<MM / 16, 256, 0, stream>>>(featP, aggF, WtH, Q1b, Q2b, Q3b, Q4b, jsf);
    k_render <<<(NNODES + 255) / 256, 256, 0, stream>>>(jsf, cluster, coords, out);
}

// Round 8
// 180.216 us; speedup vs baseline: 1.9694x; 1.1761x over previous
//
#include <hip/hip_runtime.h>
#include <hip/hip_fp16.h>
#include <cmath>

#define SSZ    128
#define SS     (SSZ*SSZ)
#define NB     8
#define NNODES (NB*SS)   /* 131072 */
#define DD     64
#define MM     16384
#define HH     100
#define BINCAP 64        /* max nodes per cluster bin */
#define KP     136       /* LDS/weight row stride in halves: 2-way bank alias only */
#define WSLOT  (112*KP)  /* one transposed weight matrix slot (halves) */

typedef _Float16 f16x8 __attribute__((ext_vector_type(8)));
typedef float    f32x4 __attribute__((ext_vector_type(4)));

// ---------------------------------------------------------------------------
// K0: transpose+convert all weight matrices to fp16 [n][k], stride KP, zero-pad.
// Slots: 0:W1 1:W2 2:W3 3:Wn 4:Wr 5:Q1 6:Q2 7:Q3 8:Q4
// ---------------------------------------------------------------------------
__global__ void k_prep(const float* __restrict__ W1, const float* __restrict__ W2,
                       const float* __restrict__ W3, const float* __restrict__ Wn,
                       const float* __restrict__ Wr, const float* __restrict__ Q1w,
                       const float* __restrict__ Q2w, const float* __restrict__ Q3w,
                       const float* __restrict__ Q4w, __half* __restrict__ Wt) {
    int idx = blockIdx.x * 256 + threadIdx.x;
    if (idx >= 9 * WSLOT) return;
    int mat = idx / WSLOT, rem = idx - mat * WSLOT;
    int n = rem / KP, k = rem - n * KP;
    const float* src; int K, N;
    switch (mat) {
        case 0: src = W1;  K = 68;  N = 100; break;
        case 1: src = W2;  K = 100; N = 100; break;
        case 2: src = W3;  K = 100; N = 64;  break;
        case 3: src = Wn;  K = 64;  N = 64;  break;
        case 4: src = Wr;  K = 64;  N = 64;  break;
        case 5: src = Q1w; K = 64;  N = 100; break;
        case 6: src = Q2w; K = 100; N = 100; break;
        case 7: src = Q3w; K = 100; N = 100; break;
        default:src = Q4w; K = 100; N = 18;  break;
    }
    float v = (n < N && k < K) ? src[k * N + n] : 0.0f;
    Wt[idx] = __float2half(v);
}

// ---------------------------------------------------------------------------
// K2: bin nodes by cluster.
// ---------------------------------------------------------------------------
__global__ void k_scatter(const int* __restrict__ cluster,
                          int* __restrict__ binCnt, int* __restrict__ nodeList) {
    int n = blockIdx.x * 256 + threadIdx.x;
    if (n >= NNODES) return;
    int c = cluster[n];
    int pos = atomicAdd(&binCnt[c], 1);
    if (pos < BINCAP) nodeList[c * BINCAP + pos] = n;
}

// ---------------------------------------------------------------------------
// K3: per-cluster segment mean. ONE WAVE per cluster: one coalesced 256B load
// pulls all member indices into lanes, shfl-broadcast, then 8 INDEPENDENT
// x-row loads per unrolled batch (chain depth 2, leaf ILP 8). No LDS.
// ---------------------------------------------------------------------------
__global__ __launch_bounds__(256) void k_reduce(
    const float* __restrict__ x, const float* __restrict__ coords,
    const int* __restrict__ binCnt, const int* __restrict__ nodeList,
    float* __restrict__ inAll, float* __restrict__ jsf) {
    const int wv = threadIdx.x >> 6, d = threadIdx.x & 63;
    const int c = blockIdx.x * 4 + wv;
    int cnt = binCnt[c];
    if (cnt > BINCAP) cnt = BINCAP;
    int nl = nodeList[c * BINCAP + d];           // member indices in lanes
    float sx = 0.0f, sc = 0.0f, sm = 0.0f;
    for (int i0 = 0; i0 < cnt; i0 += 8) {
        float v[8], cv[8];
        #pragma unroll
        for (int u = 0; u < 8; u++) {
            int i = i0 + u;
            int n = __shfl(nl, i & 63);
            if (i < cnt) {                       // wave-uniform predicate
                v[u]  = x[(size_t)n * 64 + d];
                cv[u] = (d < 2) ? coords[n * 2 + d] : 0.0f;
            } else { v[u] = 0.0f; cv[u] = 0.0f; }
        }
        #pragma unroll
        for (int u = 0; u < 8; u++) {
            sx += v[u]; sc += cv[u]; sm += cv[u] * cv[u];
        }
    }
    float fcnt = fmaxf((float)cnt, 1.0f);
    inAll[c * 68 + d] = sx / fcnt;
    if (d < 2) {
        float cent = sc / fcnt;
        inAll[c * 68 + 64 + d] = 10.0f * cent;
        inAll[c * 68 + 66 + d] = 10.0f * sm / fcnt;
        jsf[c * 20 + 18 + d] = cent;
    }
}

// ---------------------------------------------------------------------------
// MFMA GEMM stage (m89/m91-verified fragment layouts).
// ---------------------------------------------------------------------------
template<int KC, int NT>
__device__ __forceinline__ void mfma_stage(
    const _Float16* __restrict__ inBuf, _Float16* __restrict__ outBuf,
    const _Float16* __restrict__ Wt, const float* __restrict__ bias,
    int Nout, bool relu, int w, int lane) {
    const int m = lane & 15, q = lane >> 4;
    f16x8 a[KC];
    #pragma unroll
    for (int kc = 0; kc < KC; kc++)
        a[kc] = *(const f16x8*)&inBuf[m * KP + kc * 32 + q * 8];
    #pragma unroll
    for (int tt = 0; tt < (NT + 3) / 4; tt++) {
        const int t = w + tt * 4;
        if (t >= NT) break;                          // wave-uniform
        f32x4 acc = {0.0f, 0.0f, 0.0f, 0.0f};
        #pragma unroll
        for (int kc = 0; kc < KC; kc++) {
            f16x8 b = *(const f16x8*)&Wt[(16 * t + m) * KP + kc * 32 + q * 8];
            acc = __builtin_amdgcn_mfma_f32_16x16x32_f16(a[kc], b, acc, 0, 0, 0);
        }
        const int n = 16 * t + m;
        const float bb = (n < Nout) ? bias[n] : 0.0f;
        #pragma unroll
        for (int r = 0; r < 4; r++) {
            float c = acc[r] + bb;
            if (relu) c = fmaxf(c, 0.0f);
            if (n < Nout) outBuf[(q * 4 + r) * KP + n] = (_Float16)c;
        }
    }
}

// ---------------------------------------------------------------------------
// K4: MLP1 (68->100->100->64) + h@Wn (fp16) + h@Wr+bg, MFMA fp16.
// ---------------------------------------------------------------------------
__global__ __launch_bounds__(256) void k_mlp1(
    const float* __restrict__ inAll, const __half* __restrict__ WtAll,
    const float* __restrict__ b1, const float* __restrict__ b2,
    const float* __restrict__ b3, const float* __restrict__ bg,
    __half* __restrict__ hWnOut, float* __restrict__ featP) {
    __shared__ __align__(16) _Float16 sb0[16 * KP];
    __shared__ __align__(16) _Float16 sb1[16 * KP];
    const _Float16* Wt = (const _Float16*)WtAll;
    const int tid = threadIdx.x, lane = tid & 63, w = tid >> 6;
    const int c0 = blockIdx.x * 16;
    const int m = lane & 15, q = lane >> 4;

    for (int i = tid; i < 16 * 68; i += 256) {
        int r = i / 68, k = i - r * 68;
        sb0[r * KP + k] = (_Float16)inAll[(c0 + r) * 68 + k];
    }
    for (int i = tid; i < 16 * 68; i += 256) {       // sb0 cols 68..135 = 0
        int r = i / 68, k = 68 + (i - r * 68);
        sb0[r * KP + k] = (_Float16)0.0f;
    }
    for (int i = tid; i < 16 * 36; i += 256) {       // sb1 cols 100..135 = 0
        int r = i / 36, k = 100 + (i - r * 36);
        sb1[r * KP + k] = (_Float16)0.0f;
    }
    __syncthreads();

    mfma_stage<3, 7>(sb0, sb1, Wt + 0 * WSLOT, b1, 100, true,  w, lane);  // S1
    __syncthreads();
    mfma_stage<4, 7>(sb1, sb0, Wt + 1 * WSLOT, b2, 100, true,  w, lane);  // S2
    __syncthreads();
    mfma_stage<4, 4>(sb0, sb1, Wt + 2 * WSLOT, b3, 64,  false, w, lane);  // S3
    __syncthreads();

    {   // S4/S5: hWn = H3 @ Wn (fp16 out), featP = H3 @ Wr + bg
        const _Float16* Wnt = Wt + 3 * WSLOT;
        const _Float16* Wrt = Wt + 4 * WSLOT;
        f16x8 a0 = *(const f16x8*)&sb1[m * KP + q * 8];
        f16x8 a1 = *(const f16x8*)&sb1[m * KP + 32 + q * 8];
        const int t = w;
        f16x8 bn0 = *(const f16x8*)&Wnt[(16 * t + m) * KP + q * 8];
        f16x8 bn1 = *(const f16x8*)&Wnt[(16 * t + m) * KP + 32 + q * 8];
        f16x8 br0 = *(const f16x8*)&Wrt[(16 * t + m) * KP + q * 8];
        f16x8 br1 = *(const f16x8*)&Wrt[(16 * t + m) * KP + 32 + q * 8];
        f32x4 an = {0.0f, 0.0f, 0.0f, 0.0f};
        f32x4 ar = {0.0f, 0.0f, 0.0f, 0.0f};
        an = __builtin_amdgcn_mfma_f32_16x16x32_f16(a0, bn0, an, 0, 0, 0);
        an = __builtin_amdgcn_mfma_f32_16x16x32_f16(a1, bn1, an, 0, 0, 0);
        ar = __builtin_amdgcn_mfma_f32_16x16x32_f16(a0, br0, ar, 0, 0, 0);
        ar = __builtin_amdgcn_mfma_f32_16x16x32_f16(a1, br1, ar, 0, 0, 0);
        const int n = 16 * t + m;
        const float bgv = bg[n];
        #pragma unroll
        for (int r = 0; r < 4; r++) {
            int row = c0 + q * 4 + r;
            hWnOut[row * 64 + n] = __float2half(an[r]);
            featP [row * 64 + n] = ar[r] + bgv;
        }
    }
}

// ---------------------------------------------------------------------------
// K5: fused horizontal+vertical 3x3 max. One block per (8-row band x 16-col
// chunk): 8 waves build 10 hmax rows in LDS (gathers hit the L2/L3-resident
// 2 MB hWn), then each wave emits one vmax row coalesced.
// ---------------------------------------------------------------------------
__global__ __launch_bounds__(512) void k_hvmax(
    const int* __restrict__ cluster, const __half* __restrict__ hWn,
    __half* __restrict__ vmax) {
    __shared__ __half hm[10][16][64];
    const int w = threadIdx.x >> 6, lane = threadIdx.x & 63;
    const int blk  = blockIdx.x;                 // 1024 blocks
    const int b    = blk >> 7;                   // image
    const int rem  = blk & 127;
    const int r0   = (rem >> 3) << 3;            // band start row
    const int j0   = (rem & 7) << 4;             // chunk start col
    const int base = b * SS;

    for (int lr = w; lr < 10; lr += 8) {
        int gi = r0 - 1 + lr;
        if (gi < 0 || gi >= SSZ) {
            #pragma unroll
            for (int k = 0; k < 16; k++)
                hm[lr][k][lane] = __float2half(-__builtin_inff());
        } else {
            int rowbase = base + gi * SSZ;
            int jl = j0 - 1 + lane;
            int cid = 0;
            if (lane < 18 && jl >= 0 && jl < SSZ) cid = cluster[rowbase + jl];
            float val[18];
            #pragma unroll
            for (int p = 0; p < 18; p++) {
                int jp = j0 - 1 + p;
                int cp = __shfl(cid, p);
                val[p] = (jp >= 0 && jp < SSZ)
                       ? __half2float(hWn[(cp << 6) + lane])
                       : -__builtin_inff();
            }
            #pragma unroll
            for (int k = 0; k < 16; k++)
                hm[lr][k][lane] =
                    __float2half(fmaxf(fmaxf(val[k], val[k + 1]), val[k + 2]));
        }
    }
    __syncthreads();

    const int outbase = (base + (r0 + w) * SSZ + j0) << 6;
    #pragma unroll
    for (int k = 0; k < 16; k++) {
        float v = fmaxf(fmaxf(__half2float(hm[w][k][lane]),
                              __half2float(hm[w + 1][k][lane])),
                        __half2float(hm[w + 2][k][lane]));
        vmax[outbase + (k << 6) + lane] = __float2half(v);
    }
}

// ---------------------------------------------------------------------------
// K5b: per-cluster segment max. ONE WAVE per cluster, batched independent
// 128B fp16 row gathers (same ILP structure as k_reduce).
// ---------------------------------------------------------------------------
__global__ __launch_bounds__(256) void k_cmax(
    const int* __restrict__ binCnt, const int* __restrict__ nodeList,
    const __half* __restrict__ vmax, float* __restrict__ aggF) {
    const int wv = threadIdx.x >> 6, d = threadIdx.x & 63;
    const int c = blockIdx.x * 4 + wv;
    int cnt = binCnt[c];
    if (cnt > BINCAP) cnt = BINCAP;
    int nl = nodeList[c * BINCAP + d];
    float m = -__builtin_inff();
    for (int i0 = 0; i0 < cnt; i0 += 8) {
        float v[8];
        #pragma unroll
        for (int u = 0; u < 8; u++) {
            int i = i0 + u;
            int n = __shfl(nl, i & 63);
            v[u] = (i < cnt) ? __half2float(vmax[((size_t)n << 6) + d])
                             : -__builtin_inff();
        }
        #pragma unroll
        for (int u = 0; u < 8; u++) m = fmaxf(m, v[u]);
    }
    aggF[c * 64 + d] = (cnt == 0) ? 0.0f : m;    // empty segment -> 0
}

// ---------------------------------------------------------------------------
// K6: Q-MLP (64->100->100->100->18), MFMA fp16.
// ---------------------------------------------------------------------------
__global__ __launch_bounds__(256) void k_qmlp(
    const float* __restrict__ featP, const float* __restrict__ aggF,
    const __half* __restrict__ WtAll,
    const float* __restrict__ Q1b, const float* __restrict__ Q2b,
    const float* __restrict__ Q3b, const float* __restrict__ Q4b,
    float* __restrict__ jsf) {
    __shared__ __align__(16) _Float16 sb0[16 * KP];
    __shared__ __align__(16) _Float16 sb1[16 * KP];
    const _Float16* Wt = (const _Float16*)WtAll;
    const int tid = threadIdx.x, lane = tid & 63, w = tid >> 6;
    const int c0 = blockIdx.x * 16;
    const int m = lane & 15, q = lane >> 4;

    for (int i = tid; i < 16 * 64; i += 256) {
        int r = i >> 6, k = i & 63;
        int g = (c0 + r) * 64 + k;
        sb0[r * KP + k] = (_Float16)(featP[g] + aggF[g]);
    }
    for (int i = tid; i < 16 * 36; i += 256) {       // sb0 cols 100..135 = 0
        int r = i / 36, k = 100 + (i - r * 36);
        sb0[r * KP + k] = (_Float16)0.0f;
    }
    for (int i = tid; i < 16 * 36; i += 256) {       // sb1 cols 100..135 = 0
        int r = i / 36, k = 100 + (i - r * 36);
        sb1[r * KP + k] = (_Float16)0.0f;
    }
    __syncthreads();

    mfma_stage<2, 7>(sb0, sb1, Wt + 5 * WSLOT, Q1b, 100, true, w, lane);  // Q1
    __syncthreads();
    mfma_stage<4, 7>(sb1, sb0, Wt + 6 * WSLOT, Q2b, 100, true, w, lane);  // Q2
    __syncthreads();
    mfma_stage<4, 7>(sb0, sb1, Wt + 7 * WSLOT, Q3b, 100, true, w, lane);  // Q3
    __syncthreads();

    if (w < 2) {                                     // Q4: K=100, N=18
        const _Float16* Q4t = Wt + 8 * WSLOT;
        f16x8 a[4];
        #pragma unroll
        for (int kc = 0; kc < 4; kc++)
            a[kc] = *(const f16x8*)&sb1[m * KP + kc * 32 + q * 8];
        const int t = w;
        f32x4 acc = {0.0f, 0.0f, 0.0f, 0.0f};
        #pragma unroll
        for (int kc = 0; kc < 4; kc++) {
            f16x8 b = *(const f16x8*)&Q4t[(16 * t + m) * KP + kc * 32 + q * 8];
            acc = __builtin_amdgcn_mfma_f32_16x16x32_f16(a[kc], b, acc, 0, 0, 0);
        }
        const int n = 16 * t + m;
        if (n < 18) {
            const float bb = Q4b[n];
            #pragma unroll
            for (int r = 0; r < 4; r++)
                jsf[(c0 + q * 4 + r) * 20 + n] = acc[r] + bb;
        }
    }
}

// ---------------------------------------------------------------------------
// K7: per-node quadratic render
// ---------------------------------------------------------------------------
__global__ void k_render(const float* __restrict__ jsf, const int* __restrict__ cluster,
                         const float* __restrict__ coords, float* __restrict__ out) {
    int n = blockIdx.x * 256 + threadIdx.x;
    if (n >= NNODES) return;
    int c = cluster[n];
    const float* f = &jsf[c * 20];
    float gx = coords[n * 2 + 0], gy = coords[n * 2 + 1];
    float dx = gx - f[0];
    float dy = gy - f[1];
    #pragma unroll
    for (int r = 0; r < 3; r++) {
        float a   = f[2 + r * 6 + 0];
        float ah  = f[2 + r * 6 + 1];
        float aw  = f[2 + r * 6 + 2];
        float ahh = f[2 + r * 6 + 3];
        float aww = f[2 + r * 6 + 4];
        float ahw = f[2 + r * 6 + 5];
        out[n * 3 + r] = a + ah * dx + aw * dy + ahh * dx * dx + aww * dy * dy + ahw * dx * dy;
    }
}

// ---------------------------------------------------------------------------
extern "C" void kernel_launch(void* const* d_in, const int* in_sizes, int n_in,
                              void* d_out, int out_size, void* d_ws, size_t ws_size,
                              hipStream_t stream) {
    const float* x       = (const float*)d_in[0];
    const float* coords  = (const float*)d_in[1];
    const int*   cluster = (const int*)  d_in[2];
    // d_in[3], d_in[4]: edge_src/edge_dst — reconstructed analytically (L=1 stencil)
    const float* W1  = (const float*)d_in[5];
    const float* b1  = (const float*)d_in[6];
    const float* W2  = (const float*)d_in[7];
    const float* b2  = (const float*)d_in[8];
    const float* W3  = (const float*)d_in[9];
    const float* b3  = (const float*)d_in[10];
    const float* Wr  = (const float*)d_in[11];
    const float* Wn  = (const float*)d_in[12];
    const float* bg  = (const float*)d_in[13];
    const float* Q1w = (const float*)d_in[14];
    const float* Q1b = (const float*)d_in[15];
    const float* Q2w = (const float*)d_in[16];
    const float* Q2b = (const float*)d_in[17];
    const float* Q3w = (const float*)d_in[18];
    const float* Q3b = (const float*)d_in[19];
    const float* Q4w = (const float*)d_in[20];
    const float* Q4b = (const float*)d_in[21];
    float* out = (float*)d_out;

    // workspace layout (4-byte units, fp16 tail):
    // [binCnt M][nodeList M*64][inAll M*68][featP M*64][aggF M*64][jsf M*20]
    // [hWnH M*64 h][vmaxH N*64 h][WtH 9*WSLOT h]
    int*    binCnt   = (int*)d_ws;
    int*    nodeList = binCnt + MM;
    float*  inAll    = (float*)(nodeList + MM * BINCAP);
    float*  featP    = inAll + MM * 68;
    float*  aggF     = featP + MM * 64;
    float*  jsf      = aggF  + MM * 64;
    __half* hWnH     = (__half*)(jsf + MM * 20);
    __half* vmaxH    = hWnH + MM * 64;
    __half* WtH      = vmaxH + (size_t)NNODES * 64;

    hipMemsetAsync(binCnt, 0, MM * sizeof(int), stream);
    k_prep   <<<(9 * WSLOT + 255) / 256, 256, 0, stream>>>(W1, W2, W3, Wn, Wr,
                                                           Q1w, Q2w, Q3w, Q4w, WtH);
    k_scatter<<<(NNODES + 255) / 256, 256, 0, stream>>>(cluster, binCnt, nodeList);
    k_reduce <<<MM / 4, 256, 0, stream>>>(x, coords, binCnt, nodeList, inAll, jsf);
    k_mlp1   <<<MM / 16, 256, 0, stream>>>(inAll, WtH, b1, b2, b3, bg, hWnH, featP);
    k_hvmax  <<<1024, 512, 0, stream>>>(cluster, hWnH, vmaxH);
    k_cmax   <<<MM / 4, 256, 0, stream>>>(binCnt, nodeList, vmaxH, aggF);
    k_qmlp   <<<MM / 16, 256, 0, stream>>>(featP, aggF, WtH, Q1b, Q2b, Q3b, Q4b, jsf);
    k_render <<<(NNODES + 255) / 256, 256, 0, stream>>>(jsf, cluster, coords, out);
}